// Round 2
// baseline (1399.534 us; speedup 1.0000x reference)
//
#include <hip/hip_runtime.h>
#include <math.h>

#define BB   2
#define CC   256
#define NPT  4096
#define HH   4
#define DD   64
#define KNN  16
#define EPSBN 1e-5f

// ---------------- prep: fold rp BN into w1, reduce rp_w2 over heads ----------------
__global__ __launch_bounds__(256)
void prep_kernel(const float* __restrict__ rp_w1, const float* __restrict__ rp_g,
                 const float* __restrict__ rp_b,  const float* __restrict__ rp_m,
                 const float* __restrict__ rp_v,  const float* __restrict__ rp_w2,
                 float4* __restrict__ w1f, float4* __restrict__ W2t) {
  int c = threadIdx.x;
  float s  = rp_g[c] / sqrtf(rp_v[c] + EPSBN);
  float b0 = rp_b[c] - rp_m[c] * s;
  w1f[c] = make_float4(rp_w1[c*3+0]*s, rp_w1[c*3+1]*s, rp_w1[c*3+2]*s, b0);
  float a0=0.f,a1=0.f,a2=0.f,a3=0.f;
  for (int o = 0; o < 64; o++) {
    a0 += rp_w2[(      o)*CC + c];
    a1 += rp_w2[( 64 + o)*CC + c];
    a2 += rp_w2[(128 + o)*CC + c];
    a3 += rp_w2[(192 + o)*CC + c];
  }
  W2t[c] = make_float4(a0,a1,a2,a3);
}

// ---------------- KNN stage 1: 1024 blocks, each = 64 queries x (512-cand slice) ----
// grid (8 slices, 64 query groups, B). Each wave covers 128 candidates.
// Partials written transposed: D[list_entry][B*N] for coalesced merge reads.
__global__ __launch_bounds__(256)
void knn_partial_kernel(const float* __restrict__ xyz,
                        float* __restrict__ Dp, int* __restrict__ Ip) {
  __shared__ float sx[512], sy[512], sz[512];
  int s  = blockIdx.x;          // candidate slice 0..7
  int qg = blockIdx.y;          // query group 0..63
  int b  = blockIdx.z;
  const float* base = xyz + (size_t)b * 3 * NPT;
  int c0 = s * 512;
  for (int i = threadIdx.x; i < 512; i += 256) {
    sx[i] = base[c0 + i];
    sy[i] = base[NPT + c0 + i];
    sz[i] = base[2*NPT + c0 + i];
  }
  int lane = threadIdx.x & 63;
  int wv   = threadIdx.x >> 6;
  int qn   = qg * 64 + lane;
  float qx = base[qn], qy = base[NPT + qn], qz = base[2*NPT + qn];
  float qsq = qx*qx + qy*qy + qz*qz;
  __syncthreads();

  float bd[16]; int bi[16];
#pragma unroll
  for (int t = 0; t < 16; t++) { bd[t] = 3.4e38f; bi[t] = 0x7fffffff; }
  float worst = 3.4e38f; int wslot = 0; int widx = 0x7fffffff;

  int mbase = wv * 128;
#pragma unroll 4
  for (int mm = 0; mm < 128; mm++) {
    int m = mbase + mm;
    float mx = sx[m], my = sy[m], mz = sz[m];
    float msq = mx*mx + my*my + mz*mz;
    float dt  = qx*mx + qy*my + qz*mz;
    float dist = qsq + msq - 2.0f*dt;
    if (dist < worst) {           // ascending-m scan + strict < keeps lower idx on ties
      bd[wslot] = dist; bi[wslot] = c0 + m;
      worst = -3.4e38f; widx = -1;
#pragma unroll
      for (int t = 0; t < 16; t++) {
        bool better = (bd[t] > worst) || (bd[t] == worst && bi[t] > widx);
        if (better) { worst = bd[t]; widx = bi[t]; wslot = t; }
      }
    }
  }

  int gq   = b * NPT + qn;
  int lrow = (s * 4 + wv) * 16;
#pragma unroll
  for (int t = 0; t < 16; t++) {
    Dp[(size_t)(lrow + t) * (BB*NPT) + gq] = bd[t];
    Ip[(size_t)(lrow + t) * (BB*NPT) + gq] = bi[t];
  }
}

// ---------------- KNN stage 2: one thread per query merges 32 lists (512 entries) ----
__global__ __launch_bounds__(256)
void knn_merge_kernel(const float* __restrict__ Dp, const int* __restrict__ Ip,
                      int* __restrict__ idx_out) {
  int gq = blockIdx.x * 256 + threadIdx.x;   // 0..B*N-1
  float bd[16]; int bi[16];
#pragma unroll
  for (int t = 0; t < 16; t++) { bd[t] = 3.4e38f; bi[t] = 0x7fffffff; }
  float worst = 3.4e38f; int wslot = 0; int widx = 0x7fffffff;
#pragma unroll 4
  for (int e = 0; e < 512; e++) {
    float d = Dp[(size_t)e * (BB*NPT) + gq];
    int   i = Ip[(size_t)e * (BB*NPT) + gq];
    if (d < worst || (d == worst && i < widx)) {
      bd[wslot] = d; bi[wslot] = i;
      worst = -3.4e38f; widx = -1;
#pragma unroll
      for (int t = 0; t < 16; t++) {
        bool better = (bd[t] > worst) || (bd[t] == worst && bi[t] > widx);
        if (better) { worst = bd[t]; widx = bi[t]; wslot = t; }
      }
    }
  }
#pragma unroll
  for (int t = 0; t < 16; t++) idx_out[gq*16 + t] = bi[t];
}

// ---------------- fused rel-pos bias: one thread per (b,n,k) ----------------
__global__ __launch_bounds__(256)
void bias_kernel(const float* __restrict__ xyz, const int* __restrict__ idx,
                 const float4* __restrict__ w1f, const float4* __restrict__ W2t,
                 float4* __restrict__ biasB) {
  __shared__ float4 sw1[256];
  __shared__ float4 sw2[256];
  int tid = threadIdx.x;
  sw1[tid] = w1f[tid];
  sw2[tid] = W2t[tid];
  __syncthreads();
  int gid = blockIdx.x * 256 + tid;      // (b*N + n)*K + k
  int b = gid >> 16;
  int n = (gid >> 4) & 4095;
  int j = idx[gid];
  const float* base = xyz + (size_t)b * 3 * NPT;
  float rx = base[j]         - base[n];
  float ry = base[NPT + j]   - base[NPT + n];
  float rz = base[2*NPT + j] - base[2*NPT + n];
  float a0=0.f,a1=0.f,a2=0.f,a3=0.f;
#pragma unroll 8
  for (int c = 0; c < 256; c++) {
    float4 w = sw1[c];
    float t = fmaf(rx, w.x, fmaf(ry, w.y, fmaf(rz, w.z, w.w)));
    t = fmaxf(t, 0.f);
    float4 w2 = sw2[c];
    a0 = fmaf(t, w2.x, a0); a1 = fmaf(t, w2.y, a1);
    a2 = fmaf(t, w2.z, a2); a3 = fmaf(t, w2.w, a3);
  }
  biasB[gid] = make_float4(a0,a1,a2,a3);
}

// ---------------- fused attention: block per (b,n); wave = head, lane = d ----------------
__global__ __launch_bounds__(256)
void attn_kernel(const float* __restrict__ q_t, const float* __restrict__ kv_t,
                 const float* __restrict__ biasB, const int* __restrict__ idx,
                 float* __restrict__ attn_t) {
  int bn = blockIdx.x;
  int b  = bn >> 12;
  __shared__ int sidx[16];
  if (threadIdx.x < 16) sidx[threadIdx.x] = idx[bn*16 + threadIdx.x];
  __syncthreads();
  int wv = threadIdx.x >> 6;
  int c  = threadIdx.x;                          // = head*64 + d
  float qv = q_t[(size_t)bn*256 + c] * 0.125f;   // scale = d^-0.5
  size_t kvbase = (size_t)b * NPT * 512;
  float part[16];
#pragma unroll
  for (int k = 0; k < 16; k++) {
    int j = sidx[k];
    part[k] = qv * kv_t[kvbase + (size_t)j*512 + c];
  }
#pragma unroll
  for (int off = 32; off > 0; off >>= 1) {
#pragma unroll
    for (int k = 0; k < 16; k++) part[k] += __shfl_xor(part[k], off, 64);
  }
  float mx = -3.4e38f;
#pragma unroll
  for (int k = 0; k < 16; k++) {
    part[k] += biasB[(size_t)(bn*16 + k)*4 + wv];
    mx = fmaxf(mx, part[k]);
  }
  float s = 0.f;
#pragma unroll
  for (int k = 0; k < 16; k++) { part[k] = __expf(part[k] - mx); s += part[k]; }
  float inv = 1.f / s;
  float o = 0.f;
#pragma unroll
  for (int k = 0; k < 16; k++) {
    int j = sidx[k];
    o = fmaf(part[k], kv_t[kvbase + (size_t)j*512 + 256 + c], o);
  }
  attn_t[(size_t)bn*256 + c] = o * inv;
}

// ---------------- tiled SGEMM, 128m x 64n tile, 8x4 per thread ----------------
// BL=0: Bm is [Kd, N] (channel-major x);  BL=1: Bm is [N, Kd] (point-major)
// EPI: 0 plain -> Out[B][N][M];  1 +bias,relu -> Out[B][N][M]
//      2 +resid x[B][C][N], BN1 -> Out[B][N][M];  3 +bias,+resid[B][N][M], BN2 -> Out[B][M][N]
struct GemmP {
  const float* W; const float* Bm; float* Out;
  int M; int Kd;
  const float* bias; const float* resid;
  const float* bng; const float* bnb; const float* bnm; const float* bnv;
};

template<int BL, int EPI>
__global__ __launch_bounds__(256)
void gemm_kernel(GemmP p) {
  __shared__ float Ws[32][128];
  __shared__ float Xs[32][64];
  const int tid = threadIdx.x;
  const int b  = blockIdx.z;
  const int m0 = blockIdx.y * 128;
  const int n0 = blockIdx.x * 64;
  const float* Bp = p.Bm + (size_t)b * p.Kd * NPT;
  float acc[8][4];
#pragma unroll
  for (int i = 0; i < 8; i++)
#pragma unroll
    for (int j = 0; j < 4; j++) acc[i][j] = 0.f;
  const int tm = (tid & 15) * 4;
  const int tn = (tid >> 4) * 4;
  const int nch = p.Kd >> 5;
  for (int kc = 0; kc < nch; kc++) {
    const int c0 = kc * 32;
    {
      int wr = tid >> 3;
      int wc = (tid & 7) * 4;
#pragma unroll
      for (int it = 0; it < 4; it++) {
        int m = wr + it*32;
        float4 w4 = *(const float4*)(p.W + (size_t)(m0 + m)*p.Kd + c0 + wc);
        Ws[wc+0][m] = w4.x; Ws[wc+1][m] = w4.y; Ws[wc+2][m] = w4.z; Ws[wc+3][m] = w4.w;
      }
    }
    if (BL == 0) {
      int xr = tid >> 4;
      int xc = (tid & 15) * 4;
#pragma unroll
      for (int it = 0; it < 2; it++) {
        int c = xr + it*16;
        float4 v = *(const float4*)(Bp + (size_t)(c0 + c)*NPT + n0 + xc);
        Xs[c][xc+0] = v.x; Xs[c][xc+1] = v.y; Xs[c][xc+2] = v.z; Xs[c][xc+3] = v.w;
      }
    } else {
      int xr = tid >> 3;
      int xc = (tid & 7) * 4;
#pragma unroll
      for (int it = 0; it < 2; it++) {
        int n = xr + it*32;
        float4 v = *(const float4*)(Bp + (size_t)(n0 + n)*p.Kd + c0 + xc);
        Xs[xc+0][n] = v.x; Xs[xc+1][n] = v.y; Xs[xc+2][n] = v.z; Xs[xc+3][n] = v.w;
      }
    }
    __syncthreads();
#pragma unroll
    for (int kk = 0; kk < 32; kk++) {
      float4 a0 = *(const float4*)&Ws[kk][tm];
      float4 a1 = *(const float4*)&Ws[kk][tm + 64];
      float4 bv = *(const float4*)&Xs[kk][tn];
      float am[8] = {a0.x,a0.y,a0.z,a0.w,a1.x,a1.y,a1.z,a1.w};
      float bn_[4] = {bv.x,bv.y,bv.z,bv.w};
#pragma unroll
      for (int i = 0; i < 8; i++)
#pragma unroll
        for (int j = 0; j < 4; j++)
          acc[i][j] = fmaf(am[i], bn_[j], acc[i][j]);
    }
    __syncthreads();
  }
  const int gn = n0 + tn;
  if (EPI == 0 || EPI == 1) {
    float bs[8];
#pragma unroll
    for (int g = 0; g < 2; g++)
#pragma unroll
      for (int i = 0; i < 4; i++)
        bs[g*4+i] = (EPI == 1) ? p.bias[m0 + g*64 + tm + i] : 0.f;
#pragma unroll
    for (int j = 0; j < 4; j++) {
      size_t row = ((size_t)b*NPT + gn + j) * p.M + m0;
      float v[8];
#pragma unroll
      for (int i = 0; i < 8; i++) {
        float t = acc[i][j] + bs[i];
        v[i] = (EPI == 1) ? fmaxf(t, 0.f) : t;
      }
      *(float4*)(p.Out + row + tm)      = make_float4(v[0],v[1],v[2],v[3]);
      *(float4*)(p.Out + row + 64 + tm) = make_float4(v[4],v[5],v[6],v[7]);
    }
  } else if (EPI == 2) {
    float sc[8], sh[8], r[8][4];
#pragma unroll
    for (int g = 0; g < 2; g++)
#pragma unroll
      for (int i = 0; i < 4; i++) {
        int m = m0 + g*64 + tm + i;
        float s = p.bng[m] / sqrtf(p.bnv[m] + EPSBN);
        sc[g*4+i] = s; sh[g*4+i] = p.bnb[m] - p.bnm[m]*s;
        float4 xr = *(const float4*)(p.resid + ((size_t)b*CC + m)*NPT + gn);
        r[g*4+i][0]=xr.x; r[g*4+i][1]=xr.y; r[g*4+i][2]=xr.z; r[g*4+i][3]=xr.w;
      }
#pragma unroll
    for (int j = 0; j < 4; j++) {
      size_t row = ((size_t)b*NPT + gn + j) * p.M + m0;
      float v[8];
#pragma unroll
      for (int i = 0; i < 8; i++) v[i] = (acc[i][j] + r[i][j]) * sc[i] + sh[i];
      *(float4*)(p.Out + row + tm)      = make_float4(v[0],v[1],v[2],v[3]);
      *(float4*)(p.Out + row + 64 + tm) = make_float4(v[4],v[5],v[6],v[7]);
    }
  } else {  // EPI == 3 : final out [B][M][N]
    float sc[8], sh[8], bs[8], val[8][4];
#pragma unroll
    for (int g = 0; g < 2; g++)
#pragma unroll
      for (int i = 0; i < 4; i++) {
        int m = m0 + g*64 + tm + i;
        float s = p.bng[m] / sqrtf(p.bnv[m] + EPSBN);
        sc[g*4+i] = s; sh[g*4+i] = p.bnb[m] - p.bnm[m]*s;
        bs[g*4+i] = p.bias[m];
      }
#pragma unroll
    for (int j = 0; j < 4; j++) {
      size_t rrow = ((size_t)b*NPT + gn + j) * p.M + m0;
      float4 r0 = *(const float4*)(p.resid + rrow + tm);
      float4 r1 = *(const float4*)(p.resid + rrow + 64 + tm);
      float rr[8] = {r0.x,r0.y,r0.z,r0.w,r1.x,r1.y,r1.z,r1.w};
#pragma unroll
      for (int i = 0; i < 8; i++)
        val[i][j] = (acc[i][j] + bs[i] + rr[i]) * sc[i] + sh[i];
    }
#pragma unroll
    for (int g = 0; g < 2; g++)
#pragma unroll
      for (int i = 0; i < 4; i++) {
        int m = m0 + g*64 + tm + i;
        *(float4*)(p.Out + ((size_t)b*p.M + m)*NPT + gn) =
            make_float4(val[g*4+i][0], val[g*4+i][1], val[g*4+i][2], val[g*4+i][3]);
      }
  }
}

extern "C" void kernel_launch(void* const* d_in, const int* in_sizes, int n_in,
                              void* d_out, int out_size, void* d_ws, size_t ws_size,
                              hipStream_t stream) {
  const float* x     = (const float*)d_in[0];
  const float* xyz   = (const float*)d_in[1];
  const float* Wq    = (const float*)d_in[2];
  const float* Wkv   = (const float*)d_in[3];
  const float* Wproj = (const float*)d_in[4];
  const float* rp_w1 = (const float*)d_in[5];
  const float* rp_g  = (const float*)d_in[6];
  const float* rp_b  = (const float*)d_in[7];
  const float* rp_m  = (const float*)d_in[8];
  const float* rp_v  = (const float*)d_in[9];
  const float* rp_w2 = (const float*)d_in[10];
  const float* bn1_g = (const float*)d_in[11];
  const float* bn1_b = (const float*)d_in[12];
  const float* bn1_m = (const float*)d_in[13];
  const float* bn1_v = (const float*)d_in[14];
  const float* bn2_g = (const float*)d_in[15];
  const float* bn2_b = (const float*)d_in[16];
  const float* bn2_m = (const float*)d_in[17];
  const float* bn2_v = (const float*)d_in[18];
  const float* ffn_w1 = (const float*)d_in[19];
  const float* ffn_b1 = (const float*)d_in[20];
  const float* ffn_w2 = (const float*)d_in[21];
  const float* ffn_b2 = (const float*)d_in[22];

  char* ws = (char*)d_ws;
  float4* w1f   = (float4*)(ws + 0);                       //   4 KB
  float4* W2t   = (float4*)(ws + 4096);                    //   4 KB
  int*    idx   = (int*)  (ws + 8192);                     // 512 KB
  float*  q_t   = (float*)(ws + 532480);                   //   8 MB [B,N,256]
  float*  kv_t  = (float*)(ws + 8921088);                  //  16 MB [B,N,512]
  float*  biasB = (float*)(ws + 25698304);                 //   2 MB [B,N,K,H]
  float*  attn_t= (float*)(ws + 27795456);                 //   8 MB [B,N,256]
  float*  x1_t  = (float*)(ws + 36184064);                 //   8 MB [B,N,256]
  float*  h_t   = (float*)(ws + 532480);                   //  32 MB, reuses q/kv/bias/attn region (dead by then)
  // KNN scratch reuses the q_t/kv_t region (dead until the q/kv GEMMs run):
  float*  Dp    = (float*)(ws + 532480);                   //  16 MB [512][B*N]
  int*    Ip    = (int*)  (ws + 532480 + 16777216);        //  16 MB [512][B*N]

  prep_kernel<<<1, 256, 0, stream>>>(rp_w1, rp_g, rp_b, rp_m, rp_v, rp_w2, w1f, W2t);
  knn_partial_kernel<<<dim3(8, 64, BB), 256, 0, stream>>>(xyz, Dp, Ip);
  knn_merge_kernel<<<(BB*NPT)/256, 256, 0, stream>>>(Dp, Ip, idx);

  GemmP pq  = {Wq,  x, q_t,  256, 256, nullptr, nullptr, nullptr, nullptr, nullptr, nullptr};
  gemm_kernel<0,0><<<dim3(64,2,2), 256, 0, stream>>>(pq);
  GemmP pkv = {Wkv, x, kv_t, 512, 256, nullptr, nullptr, nullptr, nullptr, nullptr, nullptr};
  gemm_kernel<0,0><<<dim3(64,4,2), 256, 0, stream>>>(pkv);

  bias_kernel<<<(BB*NPT*KNN)/256, 256, 0, stream>>>(xyz, idx, w1f, W2t, (float4*)biasB);
  attn_kernel<<<BB*NPT, 256, 0, stream>>>(q_t, kv_t, biasB, idx, attn_t);

  GemmP pp = {Wproj, attn_t, x1_t, 256, 256, nullptr, x, bn1_g, bn1_b, bn1_m, bn1_v};
  gemm_kernel<1,2><<<dim3(64,2,2), 256, 0, stream>>>(pp);
  GemmP p1 = {ffn_w1, x1_t, h_t, 1024, 256, ffn_b1, nullptr, nullptr, nullptr, nullptr, nullptr};
  gemm_kernel<1,1><<<dim3(64,8,2), 256, 0, stream>>>(p1);
  GemmP p2 = {ffn_w2, h_t, (float*)d_out, 256, 1024, ffn_b2, x1_t, bn2_g, bn2_b, bn2_m, bn2_v};
  gemm_kernel<1,3><<<dim3(64,2,2), 256, 0, stream>>>(p2);
}

// Round 3
// 618.853 us; speedup vs baseline: 2.2615x; 2.2615x over previous
//
#include <hip/hip_runtime.h>
#include <math.h>

#define BB   2
#define CC   256
#define NPT  4096
#define HH   4
#define DD   64
#define KNN  16
#define EPSBN 1e-5f

// ---------------- prep: fold rp BN into w1, reduce rp_w2 over heads ----------------
__global__ __launch_bounds__(256)
void prep_kernel(const float* __restrict__ rp_w1, const float* __restrict__ rp_g,
                 const float* __restrict__ rp_b,  const float* __restrict__ rp_m,
                 const float* __restrict__ rp_v,  const float* __restrict__ rp_w2,
                 float4* __restrict__ w1f, float4* __restrict__ W2t) {
  int c = threadIdx.x;
  float s  = rp_g[c] / sqrtf(rp_v[c] + EPSBN);
  float b0 = rp_b[c] - rp_m[c] * s;
  w1f[c] = make_float4(rp_w1[c*3+0]*s, rp_w1[c*3+1]*s, rp_w1[c*3+2]*s, b0);
  float a0=0.f,a1=0.f,a2=0.f,a3=0.f;
  for (int o = 0; o < 64; o++) {
    a0 += rp_w2[(      o)*CC + c];
    a1 += rp_w2[( 64 + o)*CC + c];
    a2 += rp_w2[(128 + o)*CC + c];
    a3 += rp_w2[(192 + o)*CC + c];
  }
  W2t[c] = make_float4(a0,a1,a2,a3);
}

// ---------------- KNN stage 1: grid (8 slices, 64 qgroups, B); wave covers 128 cands ----
// Partials packed per query: Pp[gq][entry] entry=(d, idx) float2, 512 entries/query.
__global__ __launch_bounds__(256)
void knn_partial_kernel(const float* __restrict__ xyz, float4* __restrict__ Pp) {
  __shared__ float sx[512], sy[512], sz[512];
  int s  = blockIdx.x;          // candidate slice 0..7
  int qg = blockIdx.y;          // query group 0..63
  int b  = blockIdx.z;
  const float* base = xyz + (size_t)b * 3 * NPT;
  int c0 = s * 512;
  for (int i = threadIdx.x; i < 512; i += 256) {
    sx[i] = base[c0 + i];
    sy[i] = base[NPT + c0 + i];
    sz[i] = base[2*NPT + c0 + i];
  }
  int lane = threadIdx.x & 63;
  int wv   = threadIdx.x >> 6;
  int qn   = qg * 64 + lane;
  float qx = base[qn], qy = base[NPT + qn], qz = base[2*NPT + qn];
  float qsq = qx*qx + qy*qy + qz*qz;
  __syncthreads();

  float bd[16]; int bi[16];
#pragma unroll
  for (int t = 0; t < 16; t++) { bd[t] = 3.4e38f; bi[t] = 0x7fffffff; }
  float worst = 3.4e38f; int wslot = 0; int widx = 0x7fffffff;

  int mbase = wv * 128;
#pragma unroll 4
  for (int mm = 0; mm < 128; mm++) {
    int m = mbase + mm;
    float mx = sx[m], my = sy[m], mz = sz[m];
    float msq = mx*mx + my*my + mz*mz;
    float dt  = qx*mx + qy*my + qz*mz;
    float dist = qsq + msq - 2.0f*dt;
    if (dist < worst) {           // ascending-m scan + strict < keeps lower idx on ties
      bd[wslot] = dist; bi[wslot] = c0 + m;
      worst = -3.4e38f; widx = -1;
#pragma unroll
      for (int t = 0; t < 16; t++) {
        bool better = (bd[t] > worst) || (bd[t] == worst && bi[t] > widx);
        if (better) { worst = bd[t]; widx = bi[t]; wslot = t; }
      }
    }
  }

  int gq = b * NPT + qn;
  float4* out = Pp + (size_t)gq * 256 + (s*4 + wv)*8;   // 8 float4 = 16 entries, 128B contig
#pragma unroll
  for (int t = 0; t < 8; t++)
    out[t] = make_float4(bd[2*t], __int_as_float(bi[2*t]),
                         bd[2*t+1], __int_as_float(bi[2*t+1]));
}

// ---------------- KNN stage 2: one WAVE per query, 8 entries/lane, 16 select-min rounds ----
__global__ __launch_bounds__(256)
void knn_merge_kernel(const float4* __restrict__ Pp, int* __restrict__ idx_out) {
  int wv   = threadIdx.x >> 6;
  int lane = threadIdx.x & 63;
  int gq   = blockIdx.x * 4 + wv;
  float d[8]; int ii[8];
  const float4* base = Pp + (size_t)gq * 256;
#pragma unroll
  for (int j = 0; j < 4; j++) {
    float4 v = base[j*64 + lane];     // coalesced: 1KB per instruction
    d[2*j+0] = v.x; ii[2*j+0] = __float_as_int(v.y);
    d[2*j+1] = v.z; ii[2*j+1] = __float_as_int(v.w);
  }
  for (int sel = 0; sel < 16; sel++) {
    float bd = 3.5e38f; int bi = 0x7fffffff;
#pragma unroll
    for (int t = 0; t < 8; t++) {
      bool better = (d[t] < bd) || (d[t] == bd && ii[t] < bi);
      if (better) { bd = d[t]; bi = ii[t]; }
    }
#pragma unroll
    for (int off = 1; off < 64; off <<= 1) {
      float od = __shfl_xor(bd, off, 64);
      int   oi = __shfl_xor(bi, off, 64);
      if (od < bd || (od == bd && oi < bi)) { bd = od; bi = oi; }
    }
#pragma unroll
    for (int t = 0; t < 8; t++)        // candidate indices unique per query
      if (ii[t] == bi) d[t] = 3.5e38f;
    if (lane == 0) idx_out[gq*16 + sel] = bi;
  }
}

// ---------------- fused rel-pos bias: one thread per (b,n,k) ----------------
__global__ __launch_bounds__(256)
void bias_kernel(const float* __restrict__ xyz, const int* __restrict__ idx,
                 const float4* __restrict__ w1f, const float4* __restrict__ W2t,
                 float4* __restrict__ biasB) {
  __shared__ float4 sw1[256];
  __shared__ float4 sw2[256];
  int tid = threadIdx.x;
  sw1[tid] = w1f[tid];
  sw2[tid] = W2t[tid];
  __syncthreads();
  int gid = blockIdx.x * 256 + tid;      // (b*N + n)*K + k
  int b = gid >> 16;
  int n = (gid >> 4) & 4095;
  int j = idx[gid];
  const float* base = xyz + (size_t)b * 3 * NPT;
  float rx = base[j]         - base[n];
  float ry = base[NPT + j]   - base[NPT + n];
  float rz = base[2*NPT + j] - base[2*NPT + n];
  float a0=0.f,a1=0.f,a2=0.f,a3=0.f;
#pragma unroll 8
  for (int c = 0; c < 256; c++) {
    float4 w = sw1[c];
    float t = fmaf(rx, w.x, fmaf(ry, w.y, fmaf(rz, w.z, w.w)));
    t = fmaxf(t, 0.f);
    float4 w2 = sw2[c];
    a0 = fmaf(t, w2.x, a0); a1 = fmaf(t, w2.y, a1);
    a2 = fmaf(t, w2.z, a2); a3 = fmaf(t, w2.w, a3);
  }
  biasB[gid] = make_float4(a0,a1,a2,a3);
}

// ---------------- fused attention: block per (b,n); wave = head, lane = d ----------------
__global__ __launch_bounds__(256)
void attn_kernel(const float* __restrict__ q_t, const float* __restrict__ kv_t,
                 const float* __restrict__ biasB, const int* __restrict__ idx,
                 float* __restrict__ attn_t) {
  int bn = blockIdx.x;
  int b  = bn >> 12;
  __shared__ int sidx[16];
  if (threadIdx.x < 16) sidx[threadIdx.x] = idx[bn*16 + threadIdx.x];
  __syncthreads();
  int wv = threadIdx.x >> 6;
  int c  = threadIdx.x;                          // = head*64 + d
  float qv = q_t[(size_t)bn*256 + c] * 0.125f;   // scale = d^-0.5
  size_t kvbase = (size_t)b * NPT * 512;
  float part[16];
#pragma unroll
  for (int k = 0; k < 16; k++) {
    int j = sidx[k];
    part[k] = qv * kv_t[kvbase + (size_t)j*512 + c];
  }
#pragma unroll
  for (int off = 32; off > 0; off >>= 1) {
#pragma unroll
    for (int k = 0; k < 16; k++) part[k] += __shfl_xor(part[k], off, 64);
  }
  float mx = -3.4e38f;
#pragma unroll
  for (int k = 0; k < 16; k++) {
    part[k] += biasB[(size_t)(bn*16 + k)*4 + wv];
    mx = fmaxf(mx, part[k]);
  }
  float s = 0.f;
#pragma unroll
  for (int k = 0; k < 16; k++) { part[k] = __expf(part[k] - mx); s += part[k]; }
  float inv = 1.f / s;
  float o = 0.f;
#pragma unroll
  for (int k = 0; k < 16; k++) {
    int j = sidx[k];
    o = fmaf(part[k], kv_t[kvbase + (size_t)j*512 + 256 + c], o);
  }
  attn_t[(size_t)bn*256 + c] = o * inv;
}

// ---------------- tiled SGEMM, 128m x 64n tile, 8x4 per thread ----------------
// BL=0: Bm is [Kd, N] (channel-major x);  BL=1: Bm is [N, Kd] (point-major)
// EPI: 0 plain -> Out[B][N][M];  1 +bias,relu -> Out[B][N][M]
//      2 +resid x[B][C][N], BN1 -> Out[B][N][M];  3 +bias,+resid[B][N][M], BN2 -> Out[B][M][N]
struct GemmP {
  const float* W; const float* Bm; float* Out;
  int M; int Kd;
  const float* bias; const float* resid;
  const float* bng; const float* bnb; const float* bnm; const float* bnv;
};

template<int BL, int EPI>
__global__ __launch_bounds__(256)
void gemm_kernel(GemmP p) {
  __shared__ float Ws[32][128];
  __shared__ float Xs[32][64];
  const int tid = threadIdx.x;
  const int b  = blockIdx.z;
  const int m0 = blockIdx.y * 128;
  const int n0 = blockIdx.x * 64;
  const float* Bp = p.Bm + (size_t)b * p.Kd * NPT;
  float acc[8][4];
#pragma unroll
  for (int i = 0; i < 8; i++)
#pragma unroll
    for (int j = 0; j < 4; j++) acc[i][j] = 0.f;
  const int tm = (tid & 15) * 4;
  const int tn = (tid >> 4) * 4;
  const int nch = p.Kd >> 5;
  for (int kc = 0; kc < nch; kc++) {
    const int c0 = kc * 32;
    {
      int wr = tid >> 3;
      int wc = (tid & 7) * 4;
#pragma unroll
      for (int it = 0; it < 4; it++) {
        int m = wr + it*32;
        float4 w4 = *(const float4*)(p.W + (size_t)(m0 + m)*p.Kd + c0 + wc);
        Ws[wc+0][m] = w4.x; Ws[wc+1][m] = w4.y; Ws[wc+2][m] = w4.z; Ws[wc+3][m] = w4.w;
      }
    }
    if (BL == 0) {
      int xr = tid >> 4;
      int xc = (tid & 15) * 4;
#pragma unroll
      for (int it = 0; it < 2; it++) {
        int c = xr + it*16;
        float4 v = *(const float4*)(Bp + (size_t)(c0 + c)*NPT + n0 + xc);
        Xs[c][xc+0] = v.x; Xs[c][xc+1] = v.y; Xs[c][xc+2] = v.z; Xs[c][xc+3] = v.w;
      }
    } else {
      int xr = tid >> 3;
      int xc = (tid & 7) * 4;
#pragma unroll
      for (int it = 0; it < 2; it++) {
        int n = xr + it*32;
        float4 v = *(const float4*)(Bp + (size_t)(n0 + n)*p.Kd + c0 + xc);
        Xs[xc+0][n] = v.x; Xs[xc+1][n] = v.y; Xs[xc+2][n] = v.z; Xs[xc+3][n] = v.w;
      }
    }
    __syncthreads();
#pragma unroll
    for (int kk = 0; kk < 32; kk++) {
      float4 a0 = *(const float4*)&Ws[kk][tm];
      float4 a1 = *(const float4*)&Ws[kk][tm + 64];
      float4 bv = *(const float4*)&Xs[kk][tn];
      float am[8] = {a0.x,a0.y,a0.z,a0.w,a1.x,a1.y,a1.z,a1.w};
      float bn_[4] = {bv.x,bv.y,bv.z,bv.w};
#pragma unroll
      for (int i = 0; i < 8; i++)
#pragma unroll
        for (int j = 0; j < 4; j++)
          acc[i][j] = fmaf(am[i], bn_[j], acc[i][j]);
    }
    __syncthreads();
  }
  const int gn = n0 + tn;
  if (EPI == 0 || EPI == 1) {
    float bs[8];
#pragma unroll
    for (int g = 0; g < 2; g++)
#pragma unroll
      for (int i = 0; i < 4; i++)
        bs[g*4+i] = (EPI == 1) ? p.bias[m0 + g*64 + tm + i] : 0.f;
#pragma unroll
    for (int j = 0; j < 4; j++) {
      size_t row = ((size_t)b*NPT + gn + j) * p.M + m0;
      float v[8];
#pragma unroll
      for (int i = 0; i < 8; i++) {
        float t = acc[i][j] + bs[i];
        v[i] = (EPI == 1) ? fmaxf(t, 0.f) : t;
      }
      *(float4*)(p.Out + row + tm)      = make_float4(v[0],v[1],v[2],v[3]);
      *(float4*)(p.Out + row + 64 + tm) = make_float4(v[4],v[5],v[6],v[7]);
    }
  } else if (EPI == 2) {
    float sc[8], sh[8], r[8][4];
#pragma unroll
    for (int g = 0; g < 2; g++)
#pragma unroll
      for (int i = 0; i < 4; i++) {
        int m = m0 + g*64 + tm + i;
        float s = p.bng[m] / sqrtf(p.bnv[m] + EPSBN);
        sc[g*4+i] = s; sh[g*4+i] = p.bnb[m] - p.bnm[m]*s;
        float4 xr = *(const float4*)(p.resid + ((size_t)b*CC + m)*NPT + gn);
        r[g*4+i][0]=xr.x; r[g*4+i][1]=xr.y; r[g*4+i][2]=xr.z; r[g*4+i][3]=xr.w;
      }
#pragma unroll
    for (int j = 0; j < 4; j++) {
      size_t row = ((size_t)b*NPT + gn + j) * p.M + m0;
      float v[8];
#pragma unroll
      for (int i = 0; i < 8; i++) v[i] = (acc[i][j] + r[i][j]) * sc[i] + sh[i];
      *(float4*)(p.Out + row + tm)      = make_float4(v[0],v[1],v[2],v[3]);
      *(float4*)(p.Out + row + 64 + tm) = make_float4(v[4],v[5],v[6],v[7]);
    }
  } else {  // EPI == 3 : final out [B][M][N]
    float sc[8], sh[8], bs[8], val[8][4];
#pragma unroll
    for (int g = 0; g < 2; g++)
#pragma unroll
      for (int i = 0; i < 4; i++) {
        int m = m0 + g*64 + tm + i;
        float s = p.bng[m] / sqrtf(p.bnv[m] + EPSBN);
        sc[g*4+i] = s; sh[g*4+i] = p.bnb[m] - p.bnm[m]*s;
        bs[g*4+i] = p.bias[m];
      }
#pragma unroll
    for (int j = 0; j < 4; j++) {
      size_t rrow = ((size_t)b*NPT + gn + j) * p.M + m0;
      float4 r0 = *(const float4*)(p.resid + rrow + tm);
      float4 r1 = *(const float4*)(p.resid + rrow + 64 + tm);
      float rr[8] = {r0.x,r0.y,r0.z,r0.w,r1.x,r1.y,r1.z,r1.w};
#pragma unroll
      for (int i = 0; i < 8; i++)
        val[i][j] = (acc[i][j] + bs[i] + rr[i]) * sc[i] + sh[i];
    }
#pragma unroll
    for (int g = 0; g < 2; g++)
#pragma unroll
      for (int i = 0; i < 4; i++) {
        int m = m0 + g*64 + tm + i;
        *(float4*)(p.Out + ((size_t)b*p.M + m)*NPT + gn) =
            make_float4(val[g*4+i][0], val[g*4+i][1], val[g*4+i][2], val[g*4+i][3]);
      }
  }
}

extern "C" void kernel_launch(void* const* d_in, const int* in_sizes, int n_in,
                              void* d_out, int out_size, void* d_ws, size_t ws_size,
                              hipStream_t stream) {
  const float* x     = (const float*)d_in[0];
  const float* xyz   = (const float*)d_in[1];
  const float* Wq    = (const float*)d_in[2];
  const float* Wkv   = (const float*)d_in[3];
  const float* Wproj = (const float*)d_in[4];
  const float* rp_w1 = (const float*)d_in[5];
  const float* rp_g  = (const float*)d_in[6];
  const float* rp_b  = (const float*)d_in[7];
  const float* rp_m  = (const float*)d_in[8];
  const float* rp_v  = (const float*)d_in[9];
  const float* rp_w2 = (const float*)d_in[10];
  const float* bn1_g = (const float*)d_in[11];
  const float* bn1_b = (const float*)d_in[12];
  const float* bn1_m = (const float*)d_in[13];
  const float* bn1_v = (const float*)d_in[14];
  const float* bn2_g = (const float*)d_in[15];
  const float* bn2_b = (const float*)d_in[16];
  const float* bn2_m = (const float*)d_in[17];
  const float* bn2_v = (const float*)d_in[18];
  const float* ffn_w1 = (const float*)d_in[19];
  const float* ffn_b1 = (const float*)d_in[20];
  const float* ffn_w2 = (const float*)d_in[21];
  const float* ffn_b2 = (const float*)d_in[22];

  char* ws = (char*)d_ws;
  float4* w1f   = (float4*)(ws + 0);                       //   4 KB
  float4* W2t   = (float4*)(ws + 4096);                    //   4 KB
  int*    idx   = (int*)  (ws + 8192);                     // 512 KB
  float*  q_t   = (float*)(ws + 532480);                   //   8 MB [B,N,256]
  float*  kv_t  = (float*)(ws + 8921088);                  //  16 MB [B,N,512]
  float*  biasB = (float*)(ws + 25698304);                 //   2 MB [B,N,K,H]
  float*  attn_t= (float*)(ws + 27795456);                 //   8 MB [B,N,256]
  float*  x1_t  = (float*)(ws + 36184064);                 //   8 MB [B,N,256]
  float*  h_t   = (float*)(ws + 532480);                   //  32 MB, reuses q/kv/bias/attn region (dead by then)
  // KNN scratch reuses the q_t/kv_t region (dead until the q/kv GEMMs run):
  float4* Pp    = (float4*)(ws + 532480);                  //  32 MB [B*N][512] packed (d,idx)

  prep_kernel<<<1, 256, 0, stream>>>(rp_w1, rp_g, rp_b, rp_m, rp_v, rp_w2, w1f, W2t);
  knn_partial_kernel<<<dim3(8, 64, BB), 256, 0, stream>>>(xyz, Pp);
  knn_merge_kernel<<<(BB*NPT)/4, 256, 0, stream>>>(Pp, idx);

  GemmP pq  = {Wq,  x, q_t,  256, 256, nullptr, nullptr, nullptr, nullptr, nullptr, nullptr};
  gemm_kernel<0,0><<<dim3(64,2,2), 256, 0, stream>>>(pq);
  GemmP pkv = {Wkv, x, kv_t, 512, 256, nullptr, nullptr, nullptr, nullptr, nullptr, nullptr};
  gemm_kernel<0,0><<<dim3(64,4,2), 256, 0, stream>>>(pkv);

  bias_kernel<<<(BB*NPT*KNN)/256, 256, 0, stream>>>(xyz, idx, w1f, W2t, (float4*)biasB);
  attn_kernel<<<BB*NPT, 256, 0, stream>>>(q_t, kv_t, biasB, idx, attn_t);

  GemmP pp = {Wproj, attn_t, x1_t, 256, 256, nullptr, x, bn1_g, bn1_b, bn1_m, bn1_v};
  gemm_kernel<1,2><<<dim3(64,2,2), 256, 0, stream>>>(pp);
  GemmP p1 = {ffn_w1, x1_t, h_t, 1024, 256, ffn_b1, nullptr, nullptr, nullptr, nullptr, nullptr};
  gemm_kernel<1,1><<<dim3(64,8,2), 256, 0, stream>>>(p1);
  GemmP p2 = {ffn_w2, h_t, (float*)d_out, 256, 1024, ffn_b2, x1_t, bn2_g, bn2_b, bn2_m, bn2_v};
  gemm_kernel<1,3><<<dim3(64,2,2), 256, 0, stream>>>(p2);
}

// Round 4
// 544.953 us; speedup vs baseline: 2.5682x; 1.1356x over previous
//
#include <hip/hip_runtime.h>
#include <math.h>

#define BB   2
#define CC   256
#define NPT  4096
#define HH   4
#define DD   64
#define KNN  16
#define EPSBN 1e-5f

// ---------------- prep: fold rp BN into w1, reduce rp_w2 over heads ----------------
__global__ __launch_bounds__(256)
void prep_kernel(const float* __restrict__ rp_w1, const float* __restrict__ rp_g,
                 const float* __restrict__ rp_b,  const float* __restrict__ rp_m,
                 const float* __restrict__ rp_v,  const float* __restrict__ rp_w2,
                 float4* __restrict__ w1f, float4* __restrict__ W2t) {
  int c = threadIdx.x;
  float s  = rp_g[c] / sqrtf(rp_v[c] + EPSBN);
  float b0 = rp_b[c] - rp_m[c] * s;
  w1f[c] = make_float4(rp_w1[c*3+0]*s, rp_w1[c*3+1]*s, rp_w1[c*3+2]*s, b0);
  float a0=0.f,a1=0.f,a2=0.f,a3=0.f;
  for (int o = 0; o < 64; o++) {
    a0 += rp_w2[(      o)*CC + c];
    a1 += rp_w2[( 64 + o)*CC + c];
    a2 += rp_w2[(128 + o)*CC + c];
    a3 += rp_w2[(192 + o)*CC + c];
  }
  W2t[c] = make_float4(a0,a1,a2,a3);
}

// ---------------- KNN stage 1: grid (8 slices, 64 qgroups, B); wave covers 128 cands ----
// Branch-free: sorted top-16 as packed u64 keys (bits(d)<<32 | idx). d clamped >= 0 so
// float bits are order-monotonic as unsigned; low 32 bits = idx gives lax.top_k tie-break.
// Per candidate: 16-step compare-swap bubble (cmp_lt_u64 + 4 cndmask), no divergence,
// no dynamic register indexing.
__global__ __launch_bounds__(256)
void knn_partial_kernel(const float* __restrict__ xyz, float4* __restrict__ Pp) {
  __shared__ float sx[512], sy[512], sz[512];
  int s  = blockIdx.x;          // candidate slice 0..7
  int qg = blockIdx.y;          // query group 0..63
  int b  = blockIdx.z;
  const float* base = xyz + (size_t)b * 3 * NPT;
  int c0 = s * 512;
  for (int i = threadIdx.x; i < 512; i += 256) {
    sx[i] = base[c0 + i];
    sy[i] = base[NPT + c0 + i];
    sz[i] = base[2*NPT + c0 + i];
  }
  int lane = threadIdx.x & 63;
  int wv   = threadIdx.x >> 6;
  int qn   = qg * 64 + lane;
  float qx = base[qn], qy = base[NPT + qn], qz = base[2*NPT + qn];
  float qsq = qx*qx + qy*qy + qz*qz;
  __syncthreads();

  unsigned long long key[16];
#pragma unroll
  for (int t = 0; t < 16; t++) key[t] = 0xFFFFFFFFFFFFFFFFull;

  int mbase = wv * 128;
#pragma unroll 2
  for (int mm = 0; mm < 128; mm++) {
    int m = mbase + mm;
    float mx = sx[m], my = sy[m], mz = sz[m];
    float msq = mx*mx + my*my + mz*mz;
    float dt  = qx*mx + qy*my + qz*mz;
    float dist = fmaxf(qsq + msq - 2.0f*dt, 0.f);
    unsigned long long kn =
        ((unsigned long long)__float_as_uint(dist) << 32) | (unsigned int)(c0 + m);
#pragma unroll
    for (int t = 0; t < 16; t++) {
      bool c = kn < key[t];
      unsigned long long lo = c ? kn : key[t];
      kn     = c ? key[t] : kn;
      key[t] = lo;
    }
  }

  int gq = b * NPT + qn;
  float4* out = Pp + (size_t)gq * 256 + (s*4 + wv)*8;   // 8 float4 = 16 entries, 128B contig
#pragma unroll
  for (int t = 0; t < 8; t++) {
    float d0 = __uint_as_float((unsigned int)(key[2*t]   >> 32));
    float d1 = __uint_as_float((unsigned int)(key[2*t+1] >> 32));
    int   i0 = (int)(unsigned int)key[2*t];
    int   i1 = (int)(unsigned int)key[2*t+1];
    out[t] = make_float4(d0, __int_as_float(i0), d1, __int_as_float(i1));
  }
}

// ---------------- KNN stage 2: one WAVE per query, 8 entries/lane, 16 select-min rounds ----
__global__ __launch_bounds__(256)
void knn_merge_kernel(const float4* __restrict__ Pp, int* __restrict__ idx_out) {
  int wv   = threadIdx.x >> 6;
  int lane = threadIdx.x & 63;
  int gq   = blockIdx.x * 4 + wv;
  float d[8]; int ii[8];
  const float4* base = Pp + (size_t)gq * 256;
#pragma unroll
  for (int j = 0; j < 4; j++) {
    float4 v = base[j*64 + lane];     // coalesced: 1KB per instruction
    d[2*j+0] = v.x; ii[2*j+0] = __float_as_int(v.y);
    d[2*j+1] = v.z; ii[2*j+1] = __float_as_int(v.w);
  }
  for (int sel = 0; sel < 16; sel++) {
    float bd = 3.5e38f; int bi = 0x7fffffff;
#pragma unroll
    for (int t = 0; t < 8; t++) {
      bool better = (d[t] < bd) || (d[t] == bd && ii[t] < bi);
      if (better) { bd = d[t]; bi = ii[t]; }
    }
#pragma unroll
    for (int off = 1; off < 64; off <<= 1) {
      float od = __shfl_xor(bd, off, 64);
      int   oi = __shfl_xor(bi, off, 64);
      if (od < bd || (od == bd && oi < bi)) { bd = od; bi = oi; }
    }
#pragma unroll
    for (int t = 0; t < 8; t++)        // candidate indices unique per query
      if (ii[t] == bi) d[t] = 3.5e38f;
    if (lane == 0) idx_out[gq*16 + sel] = bi;
  }
}

// ---------------- fused rel-pos bias: one thread per (b,n,k) ----------------
__global__ __launch_bounds__(256)
void bias_kernel(const float* __restrict__ xyz, const int* __restrict__ idx,
                 const float4* __restrict__ w1f, const float4* __restrict__ W2t,
                 float4* __restrict__ biasB) {
  __shared__ float4 sw1[256];
  __shared__ float4 sw2[256];
  int tid = threadIdx.x;
  sw1[tid] = w1f[tid];
  sw2[tid] = W2t[tid];
  __syncthreads();
  int gid = blockIdx.x * 256 + tid;      // (b*N + n)*K + k
  int b = gid >> 16;
  int n = (gid >> 4) & 4095;
  int j = idx[gid];
  const float* base = xyz + (size_t)b * 3 * NPT;
  float rx = base[j]         - base[n];
  float ry = base[NPT + j]   - base[NPT + n];
  float rz = base[2*NPT + j] - base[2*NPT + n];
  float a0=0.f,a1=0.f,a2=0.f,a3=0.f;
#pragma unroll 8
  for (int c = 0; c < 256; c++) {
    float4 w = sw1[c];
    float t = fmaf(rx, w.x, fmaf(ry, w.y, fmaf(rz, w.z, w.w)));
    t = fmaxf(t, 0.f);
    float4 w2 = sw2[c];
    a0 = fmaf(t, w2.x, a0); a1 = fmaf(t, w2.y, a1);
    a2 = fmaf(t, w2.z, a2); a3 = fmaf(t, w2.w, a3);
  }
  biasB[gid] = make_float4(a0,a1,a2,a3);
}

// ---------------- fused attention: block per (b,n); wave = head, lane = d ----------------
__global__ __launch_bounds__(256)
void attn_kernel(const float* __restrict__ q_t, const float* __restrict__ kv_t,
                 const float* __restrict__ biasB, const int* __restrict__ idx,
                 float* __restrict__ attn_t) {
  int bn = blockIdx.x;
  int b  = bn >> 12;
  __shared__ int sidx[16];
  if (threadIdx.x < 16) sidx[threadIdx.x] = idx[bn*16 + threadIdx.x];
  __syncthreads();
  int wv = threadIdx.x >> 6;
  int c  = threadIdx.x;                          // = head*64 + d
  float qv = q_t[(size_t)bn*256 + c] * 0.125f;   // scale = d^-0.5
  size_t kvbase = (size_t)b * NPT * 512;
  float part[16];
#pragma unroll
  for (int k = 0; k < 16; k++) {
    int j = sidx[k];
    part[k] = qv * kv_t[kvbase + (size_t)j*512 + c];
  }
#pragma unroll
  for (int off = 32; off > 0; off >>= 1) {
#pragma unroll
    for (int k = 0; k < 16; k++) part[k] += __shfl_xor(part[k], off, 64);
  }
  float mx = -3.4e38f;
#pragma unroll
  for (int k = 0; k < 16; k++) {
    part[k] += biasB[(size_t)(bn*16 + k)*4 + wv];
    mx = fmaxf(mx, part[k]);
  }
  float s = 0.f;
#pragma unroll
  for (int k = 0; k < 16; k++) { part[k] = __expf(part[k] - mx); s += part[k]; }
  float inv = 1.f / s;
  float o = 0.f;
#pragma unroll
  for (int k = 0; k < 16; k++) {
    int j = sidx[k];
    o = fmaf(part[k], kv_t[kvbase + (size_t)j*512 + 256 + c], o);
  }
  attn_t[(size_t)bn*256 + c] = o * inv;
}

// ---------------- tiled SGEMM, 128m x 64n tile, 8x4 per thread ----------------
// BL=0: Bm is [Kd, N] (channel-major x);  BL=1: Bm is [N, Kd] (point-major)
// EPI: 0 plain -> Out[B][N][M];  1 +bias,relu -> Out[B][N][M]
//      2 +resid x[B][C][N], BN1 -> Out[B][N][M];  3 +bias,+resid[B][N][M], BN2 -> Out[B][M][N]
struct GemmP {
  const float* W; const float* Bm; float* Out;
  int M; int Kd;
  const float* bias; const float* resid;
  const float* bng; const float* bnb; const float* bnm; const float* bnv;
};

template<int BL, int EPI>
__global__ __launch_bounds__(256)
void gemm_kernel(GemmP p) {
  __shared__ float Ws[32][128];
  __shared__ float Xs[32][64];
  const int tid = threadIdx.x;
  const int b  = blockIdx.z;
  const int m0 = blockIdx.y * 128;
  const int n0 = blockIdx.x * 64;
  const float* Bp = p.Bm + (size_t)b * p.Kd * NPT;
  float acc[8][4];
#pragma unroll
  for (int i = 0; i < 8; i++)
#pragma unroll
    for (int j = 0; j < 4; j++) acc[i][j] = 0.f;
  const int tm = (tid & 15) * 4;
  const int tn = (tid >> 4) * 4;
  const int nch = p.Kd >> 5;
  for (int kc = 0; kc < nch; kc++) {
    const int c0 = kc * 32;
    {
      int wr = tid >> 3;
      int wc = (tid & 7) * 4;
#pragma unroll
      for (int it = 0; it < 4; it++) {
        int m = wr + it*32;
        float4 w4 = *(const float4*)(p.W + (size_t)(m0 + m)*p.Kd + c0 + wc);
        Ws[wc+0][m] = w4.x; Ws[wc+1][m] = w4.y; Ws[wc+2][m] = w4.z; Ws[wc+3][m] = w4.w;
      }
    }
    if (BL == 0) {
      int xr = tid >> 4;
      int xc = (tid & 15) * 4;
#pragma unroll
      for (int it = 0; it < 2; it++) {
        int c = xr + it*16;
        float4 v = *(const float4*)(Bp + (size_t)(c0 + c)*NPT + n0 + xc);
        Xs[c][xc+0] = v.x; Xs[c][xc+1] = v.y; Xs[c][xc+2] = v.z; Xs[c][xc+3] = v.w;
      }
    } else {
      int xr = tid >> 3;
      int xc = (tid & 7) * 4;
#pragma unroll
      for (int it = 0; it < 2; it++) {
        int n = xr + it*32;
        float4 v = *(const float4*)(Bp + (size_t)(n0 + n)*p.Kd + c0 + xc);
        Xs[xc+0][n] = v.x; Xs[xc+1][n] = v.y; Xs[xc+2][n] = v.z; Xs[xc+3][n] = v.w;
      }
    }
    __syncthreads();
#pragma unroll
    for (int kk = 0; kk < 32; kk++) {
      float4 a0 = *(const float4*)&Ws[kk][tm];
      float4 a1 = *(const float4*)&Ws[kk][tm + 64];
      float4 bv = *(const float4*)&Xs[kk][tn];
      float am[8] = {a0.x,a0.y,a0.z,a0.w,a1.x,a1.y,a1.z,a1.w};
      float bn_[4] = {bv.x,bv.y,bv.z,bv.w};
#pragma unroll
      for (int i = 0; i < 8; i++)
#pragma unroll
        for (int j = 0; j < 4; j++)
          acc[i][j] = fmaf(am[i], bn_[j], acc[i][j]);
    }
    __syncthreads();
  }
  const int gn = n0 + tn;
  if (EPI == 0 || EPI == 1) {
    float bs[8];
#pragma unroll
    for (int g = 0; g < 2; g++)
#pragma unroll
      for (int i = 0; i < 4; i++)
        bs[g*4+i] = (EPI == 1) ? p.bias[m0 + g*64 + tm + i] : 0.f;
#pragma unroll
    for (int j = 0; j < 4; j++) {
      size_t row = ((size_t)b*NPT + gn + j) * p.M + m0;
      float v[8];
#pragma unroll
      for (int i = 0; i < 8; i++) {
        float t = acc[i][j] + bs[i];
        v[i] = (EPI == 1) ? fmaxf(t, 0.f) : t;
      }
      *(float4*)(p.Out + row + tm)      = make_float4(v[0],v[1],v[2],v[3]);
      *(float4*)(p.Out + row + 64 + tm) = make_float4(v[4],v[5],v[6],v[7]);
    }
  } else if (EPI == 2) {
    float sc[8], sh[8], r[8][4];
#pragma unroll
    for (int g = 0; g < 2; g++)
#pragma unroll
      for (int i = 0; i < 4; i++) {
        int m = m0 + g*64 + tm + i;
        float s = p.bng[m] / sqrtf(p.bnv[m] + EPSBN);
        sc[g*4+i] = s; sh[g*4+i] = p.bnb[m] - p.bnm[m]*s;
        float4 xr = *(const float4*)(p.resid + ((size_t)b*CC + m)*NPT + gn);
        r[g*4+i][0]=xr.x; r[g*4+i][1]=xr.y; r[g*4+i][2]=xr.z; r[g*4+i][3]=xr.w;
      }
#pragma unroll
    for (int j = 0; j < 4; j++) {
      size_t row = ((size_t)b*NPT + gn + j) * p.M + m0;
      float v[8];
#pragma unroll
      for (int i = 0; i < 8; i++) v[i] = (acc[i][j] + r[i][j]) * sc[i] + sh[i];
      *(float4*)(p.Out + row + tm)      = make_float4(v[0],v[1],v[2],v[3]);
      *(float4*)(p.Out + row + 64 + tm) = make_float4(v[4],v[5],v[6],v[7]);
    }
  } else {  // EPI == 3 : final out [B][M][N]
    float sc[8], sh[8], bs[8], val[8][4];
#pragma unroll
    for (int g = 0; g < 2; g++)
#pragma unroll
      for (int i = 0; i < 4; i++) {
        int m = m0 + g*64 + tm + i;
        float s = p.bng[m] / sqrtf(p.bnv[m] + EPSBN);
        sc[g*4+i] = s; sh[g*4+i] = p.bnb[m] - p.bnm[m]*s;
        bs[g*4+i] = p.bias[m];
      }
#pragma unroll
    for (int j = 0; j < 4; j++) {
      size_t rrow = ((size_t)b*NPT + gn + j) * p.M + m0;
      float4 r0 = *(const float4*)(p.resid + rrow + tm);
      float4 r1 = *(const float4*)(p.resid + rrow + 64 + tm);
      float rr[8] = {r0.x,r0.y,r0.z,r0.w,r1.x,r1.y,r1.z,r1.w};
#pragma unroll
      for (int i = 0; i < 8; i++)
        val[i][j] = (acc[i][j] + bs[i] + rr[i]) * sc[i] + sh[i];
    }
#pragma unroll
    for (int g = 0; g < 2; g++)
#pragma unroll
      for (int i = 0; i < 4; i++) {
        int m = m0 + g*64 + tm + i;
        *(float4*)(p.Out + ((size_t)b*p.M + m)*NPT + gn) =
            make_float4(val[g*4+i][0], val[g*4+i][1], val[g*4+i][2], val[g*4+i][3]);
      }
  }
}

extern "C" void kernel_launch(void* const* d_in, const int* in_sizes, int n_in,
                              void* d_out, int out_size, void* d_ws, size_t ws_size,
                              hipStream_t stream) {
  const float* x     = (const float*)d_in[0];
  const float* xyz   = (const float*)d_in[1];
  const float* Wq    = (const float*)d_in[2];
  const float* Wkv   = (const float*)d_in[3];
  const float* Wproj = (const float*)d_in[4];
  const float* rp_w1 = (const float*)d_in[5];
  const float* rp_g  = (const float*)d_in[6];
  const float* rp_b  = (const float*)d_in[7];
  const float* rp_m  = (const float*)d_in[8];
  const float* rp_v  = (const float*)d_in[9];
  const float* rp_w2 = (const float*)d_in[10];
  const float* bn1_g = (const float*)d_in[11];
  const float* bn1_b = (const float*)d_in[12];
  const float* bn1_m = (const float*)d_in[13];
  const float* bn1_v = (const float*)d_in[14];
  const float* bn2_g = (const float*)d_in[15];
  const float* bn2_b = (const float*)d_in[16];
  const float* bn2_m = (const float*)d_in[17];
  const float* bn2_v = (const float*)d_in[18];
  const float* ffn_w1 = (const float*)d_in[19];
  const float* ffn_b1 = (const float*)d_in[20];
  const float* ffn_w2 = (const float*)d_in[21];
  const float* ffn_b2 = (const float*)d_in[22];

  char* ws = (char*)d_ws;
  float4* w1f   = (float4*)(ws + 0);                       //   4 KB
  float4* W2t   = (float4*)(ws + 4096);                    //   4 KB
  int*    idx   = (int*)  (ws + 8192);                     // 512 KB
  float*  q_t   = (float*)(ws + 532480);                   //   8 MB [B,N,256]
  float*  kv_t  = (float*)(ws + 8921088);                  //  16 MB [B,N,512]
  float*  biasB = (float*)(ws + 25698304);                 //   2 MB [B,N,K,H]
  float*  attn_t= (float*)(ws + 27795456);                 //   8 MB [B,N,256]
  float*  x1_t  = (float*)(ws + 36184064);                 //   8 MB [B,N,256]
  float*  h_t   = (float*)(ws + 532480);                   //  32 MB, reuses q/kv/bias/attn region (dead by then)
  // KNN scratch reuses the q_t/kv_t region (dead until the q/kv GEMMs run):
  float4* Pp    = (float4*)(ws + 532480);                  //  32 MB [B*N][512] packed (d,idx)

  prep_kernel<<<1, 256, 0, stream>>>(rp_w1, rp_g, rp_b, rp_m, rp_v, rp_w2, w1f, W2t);
  knn_partial_kernel<<<dim3(8, 64, BB), 256, 0, stream>>>(xyz, Pp);
  knn_merge_kernel<<<(BB*NPT)/4, 256, 0, stream>>>(Pp, idx);

  GemmP pq  = {Wq,  x, q_t,  256, 256, nullptr, nullptr, nullptr, nullptr, nullptr, nullptr};
  gemm_kernel<0,0><<<dim3(64,2,2), 256, 0, stream>>>(pq);
  GemmP pkv = {Wkv, x, kv_t, 512, 256, nullptr, nullptr, nullptr, nullptr, nullptr, nullptr};
  gemm_kernel<0,0><<<dim3(64,4,2), 256, 0, stream>>>(pkv);

  bias_kernel<<<(BB*NPT*KNN)/256, 256, 0, stream>>>(xyz, idx, w1f, W2t, (float4*)biasB);
  attn_kernel<<<BB*NPT, 256, 0, stream>>>(q_t, kv_t, biasB, idx, attn_t);

  GemmP pp = {Wproj, attn_t, x1_t, 256, 256, nullptr, x, bn1_g, bn1_b, bn1_m, bn1_v};
  gemm_kernel<1,2><<<dim3(64,2,2), 256, 0, stream>>>(pp);
  GemmP p1 = {ffn_w1, x1_t, h_t, 1024, 256, ffn_b1, nullptr, nullptr, nullptr, nullptr, nullptr};
  gemm_kernel<1,1><<<dim3(64,8,2), 256, 0, stream>>>(p1);
  GemmP p2 = {ffn_w2, h_t, (float*)d_out, 256, 1024, ffn_b2, x1_t, bn2_g, bn2_b, bn2_m, bn2_v};
  gemm_kernel<1,3><<<dim3(64,2,2), 256, 0, stream>>>(p2);
}

// Round 5
// 354.619 us; speedup vs baseline: 3.9466x; 1.5367x over previous
//
#include <hip/hip_runtime.h>
#include <math.h>

#define BB   2
#define CC   256
#define NPT  4096
#define HH   4
#define DD   64
#define KNN  16
#define EPSBN 1e-5f

typedef __attribute__((ext_vector_type(8))) short short8;
typedef __attribute__((ext_vector_type(4))) float f32x4;

__device__ __forceinline__ unsigned short f2b(float f) {
  union { float f; unsigned int u; } v; v.f = f;
  unsigned int r = (v.u + 0x7FFFu + ((v.u >> 16) & 1u)) >> 16;
  return (unsigned short)r;
}
__device__ __forceinline__ float b2f(unsigned short h) {
  union { unsigned int u; float f; } v; v.u = ((unsigned int)h) << 16;
  return v.f;
}

// ---------------- prep: fold rp BN into w1, reduce rp_w2 over heads ----------------
__global__ __launch_bounds__(256)
void prep_kernel(const float* __restrict__ rp_w1, const float* __restrict__ rp_g,
                 const float* __restrict__ rp_b,  const float* __restrict__ rp_m,
                 const float* __restrict__ rp_v,  const float* __restrict__ rp_w2,
                 float4* __restrict__ w1f, float4* __restrict__ W2t) {
  int c = threadIdx.x;
  float s  = rp_g[c] / sqrtf(rp_v[c] + EPSBN);
  float b0 = rp_b[c] - rp_m[c] * s;
  w1f[c] = make_float4(rp_w1[c*3+0]*s, rp_w1[c*3+1]*s, rp_w1[c*3+2]*s, b0);
  float a0=0.f,a1=0.f,a2=0.f,a3=0.f;
  for (int o = 0; o < 64; o++) {
    a0 += rp_w2[(      o)*CC + c];
    a1 += rp_w2[( 64 + o)*CC + c];
    a2 += rp_w2[(128 + o)*CC + c];
    a3 += rp_w2[(192 + o)*CC + c];
  }
  W2t[c] = make_float4(a0,a1,a2,a3);
}

// ---------------- cast weights to bf16 (qkv rows concatenated [Wq;Wkv]) ------------
__global__ __launch_bounds__(256)
void wcast_kernel(const float* __restrict__ Wq, const float* __restrict__ Wkv,
                  const float* __restrict__ Wp, const float* __restrict__ W1,
                  const float* __restrict__ W2,
                  unsigned short* __restrict__ oQKV, unsigned short* __restrict__ oP,
                  unsigned short* __restrict__ o1,   unsigned short* __restrict__ o2) {
  int i = blockIdx.x * 256 + threadIdx.x;          // 786432 total
  if (i < 65536)        oQKV[i] = f2b(Wq[i]);
  else if (i < 196608)  oQKV[i] = f2b(Wkv[i - 65536]);
  else if (i < 262144)  oP[i - 196608] = f2b(Wp[i - 196608]);
  else if (i < 524288)  o1[i - 262144] = f2b(W1[i - 262144]);
  else                  o2[i - 524288] = f2b(W2[i - 524288]);
}

// ---------------- transpose+cast x: [B][C][N] fp32 -> [B][N][C] bf16 + fp32 --------
__global__ __launch_bounds__(256)
void xcast_kernel(const float* __restrict__ x, unsigned short* __restrict__ xb,
                  float* __restrict__ xf) {
  __shared__ float T[64][65];
  int n0 = blockIdx.x * 64, c0 = blockIdx.y * 64, bb = blockIdx.z;
  int tid = threadIdx.x;
  {
    int crow = tid >> 2, ns = (tid & 3) * 16;
    const float* xp = x + ((size_t)(bb*CC + c0 + crow))*NPT + n0 + ns;
#pragma unroll
    for (int i = 0; i < 4; i++) {
      float4 v = ((const float4*)xp)[i];
      T[crow][ns + i*4 + 0] = v.x; T[crow][ns + i*4 + 1] = v.y;
      T[crow][ns + i*4 + 2] = v.z; T[crow][ns + i*4 + 3] = v.w;
    }
  }
  __syncthreads();
  {
    int nrow = tid >> 2, cs = (tid & 3) * 16;
    float vals[16];
#pragma unroll
    for (int i = 0; i < 16; i++) vals[i] = T[cs + i][nrow];
    size_t orow = ((size_t)(bb*NPT + n0 + nrow))*CC + c0 + cs;
#pragma unroll
    for (int i = 0; i < 4; i++)
      *(float4*)&xf[orow + i*4] = make_float4(vals[i*4], vals[i*4+1], vals[i*4+2], vals[i*4+3]);
    unsigned short us[16];
#pragma unroll
    for (int i = 0; i < 16; i++) us[i] = f2b(vals[i]);
    *(uint4*)&xb[orow]     = *(const uint4*)&us[0];
    *(uint4*)&xb[orow + 8] = *(const uint4*)&us[8];
  }
}

// ---------------- KNN stage 1 (unchanged from R3) ----------------
__global__ __launch_bounds__(256)
void knn_partial_kernel(const float* __restrict__ xyz, float4* __restrict__ Pp) {
  __shared__ float sx[512], sy[512], sz[512];
  int s  = blockIdx.x;
  int qg = blockIdx.y;
  int b  = blockIdx.z;
  const float* base = xyz + (size_t)b * 3 * NPT;
  int c0 = s * 512;
  for (int i = threadIdx.x; i < 512; i += 256) {
    sx[i] = base[c0 + i];
    sy[i] = base[NPT + c0 + i];
    sz[i] = base[2*NPT + c0 + i];
  }
  int lane = threadIdx.x & 63;
  int wv   = threadIdx.x >> 6;
  int qn   = qg * 64 + lane;
  float qx = base[qn], qy = base[NPT + qn], qz = base[2*NPT + qn];
  float qsq = qx*qx + qy*qy + qz*qz;
  __syncthreads();

  unsigned long long key[16];
#pragma unroll
  for (int t = 0; t < 16; t++) key[t] = 0xFFFFFFFFFFFFFFFFull;

  int mbase = wv * 128;
#pragma unroll 2
  for (int mm = 0; mm < 128; mm++) {
    int m = mbase + mm;
    float mx = sx[m], my = sy[m], mz = sz[m];
    float msq = mx*mx + my*my + mz*mz;
    float dt  = qx*mx + qy*my + qz*mz;
    float dist = fmaxf(qsq + msq - 2.0f*dt, 0.f);
    unsigned long long kn =
        ((unsigned long long)__float_as_uint(dist) << 32) | (unsigned int)(c0 + m);
#pragma unroll
    for (int t = 0; t < 16; t++) {
      bool c = kn < key[t];
      unsigned long long lo = c ? kn : key[t];
      kn     = c ? key[t] : kn;
      key[t] = lo;
    }
  }

  int gq = b * NPT + qn;
  float4* out = Pp + (size_t)gq * 256 + (s*4 + wv)*8;
#pragma unroll
  for (int t = 0; t < 8; t++) {
    float d0 = __uint_as_float((unsigned int)(key[2*t]   >> 32));
    float d1 = __uint_as_float((unsigned int)(key[2*t+1] >> 32));
    int   i0 = (int)(unsigned int)key[2*t];
    int   i1 = (int)(unsigned int)key[2*t+1];
    out[t] = make_float4(d0, __int_as_float(i0), d1, __int_as_float(i1));
  }
}

// ---------------- KNN stage 2 (unchanged from R3) ----------------
__global__ __launch_bounds__(256)
void knn_merge_kernel(const float4* __restrict__ Pp, int* __restrict__ idx_out) {
  int wv   = threadIdx.x >> 6;
  int lane = threadIdx.x & 63;
  int gq   = blockIdx.x * 4 + wv;
  float d[8]; int ii[8];
  const float4* base = Pp + (size_t)gq * 256;
#pragma unroll
  for (int j = 0; j < 4; j++) {
    float4 v = base[j*64 + lane];
    d[2*j+0] = v.x; ii[2*j+0] = __float_as_int(v.y);
    d[2*j+1] = v.z; ii[2*j+1] = __float_as_int(v.w);
  }
  for (int sel = 0; sel < 16; sel++) {
    float bd = 3.5e38f; int bi = 0x7fffffff;
#pragma unroll
    for (int t = 0; t < 8; t++) {
      bool better = (d[t] < bd) || (d[t] == bd && ii[t] < bi);
      if (better) { bd = d[t]; bi = ii[t]; }
    }
#pragma unroll
    for (int off = 1; off < 64; off <<= 1) {
      float od = __shfl_xor(bd, off, 64);
      int   oi = __shfl_xor(bi, off, 64);
      if (od < bd || (od == bd && oi < bi)) { bd = od; bi = oi; }
    }
#pragma unroll
    for (int t = 0; t < 8; t++)
      if (ii[t] == bi) d[t] = 3.5e38f;
    if (lane == 0) idx_out[gq*16 + sel] = bi;
  }
}

// ---------------- fused rel-pos bias (unchanged) ----------------
__global__ __launch_bounds__(256)
void bias_kernel(const float* __restrict__ xyz, const int* __restrict__ idx,
                 const float4* __restrict__ w1f, const float4* __restrict__ W2t,
                 float4* __restrict__ biasB) {
  __shared__ float4 sw1[256];
  __shared__ float4 sw2[256];
  int tid = threadIdx.x;
  sw1[tid] = w1f[tid];
  sw2[tid] = W2t[tid];
  __syncthreads();
  int gid = blockIdx.x * 256 + tid;
  int b = gid >> 16;
  int n = (gid >> 4) & 4095;
  int j = idx[gid];
  const float* base = xyz + (size_t)b * 3 * NPT;
  float rx = base[j]         - base[n];
  float ry = base[NPT + j]   - base[NPT + n];
  float rz = base[2*NPT + j] - base[2*NPT + n];
  float a0=0.f,a1=0.f,a2=0.f,a3=0.f;
#pragma unroll 8
  for (int c = 0; c < 256; c++) {
    float4 w = sw1[c];
    float t = fmaf(rx, w.x, fmaf(ry, w.y, fmaf(rz, w.z, w.w)));
    t = fmaxf(t, 0.f);
    float4 w2 = sw2[c];
    a0 = fmaf(t, w2.x, a0); a1 = fmaf(t, w2.y, a1);
    a2 = fmaf(t, w2.z, a2); a3 = fmaf(t, w2.w, a3);
  }
  biasB[gid] = make_float4(a0,a1,a2,a3);
}

// ---------------- fused attention: qkv bf16 [B][N][768]; out bf16 [B][N][256] -------
__global__ __launch_bounds__(256)
void attn_kernel(const unsigned short* __restrict__ qkv, const float* __restrict__ biasB,
                 const int* __restrict__ idx, unsigned short* __restrict__ attn_b) {
  int bn = blockIdx.x;
  int b  = bn >> 12;
  __shared__ int sidx[16];
  if (threadIdx.x < 16) sidx[threadIdx.x] = idx[bn*16 + threadIdx.x];
  __syncthreads();
  int wv = threadIdx.x >> 6;
  int c  = threadIdx.x;
  float qv = b2f(qkv[(size_t)bn*768 + c]) * 0.125f;
  size_t base = (size_t)(b*NPT) * 768;
  float part[16];
#pragma unroll
  for (int k = 0; k < 16; k++) {
    int j = sidx[k];
    part[k] = qv * b2f(qkv[base + (size_t)j*768 + 256 + c]);
  }
#pragma unroll
  for (int off = 32; off > 0; off >>= 1) {
#pragma unroll
    for (int k = 0; k < 16; k++) part[k] += __shfl_xor(part[k], off, 64);
  }
  float mx = -3.4e38f;
#pragma unroll
  for (int k = 0; k < 16; k++) {
    part[k] += biasB[(size_t)(bn*16 + k)*4 + wv];
    mx = fmaxf(mx, part[k]);
  }
  float s = 0.f;
#pragma unroll
  for (int k = 0; k < 16; k++) { part[k] = __expf(part[k] - mx); s += part[k]; }
  float inv = 1.f / s;
  float o = 0.f;
#pragma unroll
  for (int k = 0; k < 16; k++) {
    int j = sidx[k];
    o = fmaf(part[k], b2f(qkv[base + (size_t)j*768 + 512 + c]), o);
  }
  attn_b[(size_t)bn*256 + c] = f2b(o * inv);
}

// ---------------- MFMA bf16 GEMM: D[n][m] = A[n][k] * W[m][k] ----------------
// Block: 128 n x 64 m, 4 waves (wave = 32 n x 64 m = 2x4 16x16 tiles), BK=32.
// A point-major bf16 [B][N][K]; W bf16 [M][K]. Fragments k-contiguous (quad*8+j).
// D: col(lane&15)=m-in-tile, row(quad*4+reg)=n-in-tile.
// EPI: 0 -> OutB bf16 [B][N][M]
//      1 bias+relu -> OutB bf16 [B][N][M]
//      2 (+resid fp32 [B][N][M], BN) -> OutF fp32 + OutB bf16 [B][N][M]
//      3 (+bias +resid fp32 [B][N][M], BN) -> OutF fp32 [B][M][N] (LDS transpose)
struct MG {
  const unsigned short* A; const unsigned short* Wt; int K; int M;
  unsigned short* OutB; float* OutF;
  const float* bias; const float* resid;
  const float* bng; const float* bnb; const float* bnm; const float* bnv;
};

template<int EPI>
__global__ __launch_bounds__(256)
void mgemm_kernel(MG p) {
  __shared__ unsigned short As[128][40];
  __shared__ unsigned short Bs[64][40];
  const int tid  = threadIdx.x;
  const int bb   = blockIdx.z;
  const int n0   = blockIdx.x * 128;
  const int m0   = blockIdx.y * 64;
  const int lane = tid & 63;
  const int wv   = tid >> 6;
  const int l15  = lane & 15;
  const int quad = lane >> 4;
  const int K    = p.K;

  f32x4 acc[2][4];
#pragma unroll
  for (int i = 0; i < 2; i++)
#pragma unroll
    for (int j = 0; j < 4; j++) acc[i][j] = (f32x4){0.f, 0.f, 0.f, 0.f};

  const int arow = tid >> 1, ahalf = tid & 1;
  const int wrow = tid >> 2, wseg = tid & 3;
  const unsigned short* Ap = p.A  + (size_t)(bb*NPT + n0 + arow)*K + ahalf*16;
  const unsigned short* Wp = p.Wt + (size_t)(m0 + wrow)*K + wseg*8;

  for (int c0 = 0; c0 < K; c0 += 32) {
    uint4 va0 = *(const uint4*)(Ap + c0);
    uint4 va1 = *(const uint4*)(Ap + c0 + 8);
    uint4 vw  = *(const uint4*)(Wp + c0);
    *(uint4*)&As[arow][ahalf*16]     = va0;
    *(uint4*)&As[arow][ahalf*16 + 8] = va1;
    *(uint4*)&Bs[wrow][wseg*8]       = vw;
    __syncthreads();
    short8 bf[4];
#pragma unroll
    for (int mt = 0; mt < 4; mt++)
      bf[mt] = *(const short8*)&Bs[mt*16 + l15][quad*8];
#pragma unroll
    for (int nt = 0; nt < 2; nt++) {
      short8 af = *(const short8*)&As[wv*32 + nt*16 + l15][quad*8];
#pragma unroll
      for (int mt = 0; mt < 4; mt++)
        acc[nt][mt] = __builtin_amdgcn_mfma_f32_16x16x32_bf16(af, bf[mt], acc[nt][mt], 0, 0, 0);
    }
    __syncthreads();
  }

  if (EPI == 0 || EPI == 1) {
    float bs[4];
#pragma unroll
    for (int mt = 0; mt < 4; mt++)
      bs[mt] = (EPI == 1) ? p.bias[m0 + mt*16 + l15] : 0.f;
#pragma unroll
    for (int nt = 0; nt < 2; nt++)
#pragma unroll
      for (int reg = 0; reg < 4; reg++) {
        size_t row = ((size_t)(bb*NPT + n0 + wv*32 + nt*16 + quad*4 + reg))*p.M + m0;
#pragma unroll
        for (int mt = 0; mt < 4; mt++) {
          float v = acc[nt][mt][reg] + bs[mt];
          if (EPI == 1) v = fmaxf(v, 0.f);
          p.OutB[row + mt*16 + l15] = f2b(v);
        }
      }
  } else if (EPI == 2) {
    float sc[4], sh[4];
#pragma unroll
    for (int mt = 0; mt < 4; mt++) {
      int m = m0 + mt*16 + l15;
      float s = p.bng[m] / sqrtf(p.bnv[m] + EPSBN);
      sc[mt] = s; sh[mt] = p.bnb[m] - p.bnm[m]*s;
    }
#pragma unroll
    for (int nt = 0; nt < 2; nt++)
#pragma unroll
      for (int reg = 0; reg < 4; reg++) {
        size_t row = ((size_t)(bb*NPT + n0 + wv*32 + nt*16 + quad*4 + reg))*p.M + m0;
#pragma unroll
        for (int mt = 0; mt < 4; mt++) {
          float r = p.resid[row + mt*16 + l15];
          float v = (acc[nt][mt][reg] + r)*sc[mt] + sh[mt];
          p.OutF[row + mt*16 + l15] = v;
          p.OutB[row + mt*16 + l15] = f2b(v);
        }
      }
  } else {  // EPI == 3
    __shared__ float Tb[4][4][16*17];
    float sc[4], sh[4], bs[4];
#pragma unroll
    for (int mt = 0; mt < 4; mt++) {
      int m = m0 + mt*16 + l15;
      float s = p.bng[m] / sqrtf(p.bnv[m] + EPSBN);
      sc[mt] = s; sh[mt] = p.bnb[m] - p.bnm[m]*s;
      bs[mt] = p.bias[m];
    }
#pragma unroll
    for (int nt = 0; nt < 2; nt++) {
#pragma unroll
      for (int reg = 0; reg < 4; reg++) {
        size_t row = ((size_t)(bb*NPT + n0 + wv*32 + nt*16 + quad*4 + reg))*p.M + m0;
#pragma unroll
        for (int mt = 0; mt < 4; mt++) {
          float r = p.resid[row + mt*16 + l15];
          float v = (acc[nt][mt][reg] + bs[mt] + r)*sc[mt] + sh[mt];
          Tb[wv][mt][(quad*4 + reg)*17 + l15] = v;
        }
      }
      __syncthreads();
#pragma unroll
      for (int mt = 0; mt < 4; mt++)
#pragma unroll
        for (int reg = 0; reg < 4; reg++) {
          float v = Tb[wv][mt][l15*17 + quad*4 + reg];
          p.OutF[((size_t)(bb*p.M + m0 + mt*16 + quad*4 + reg))*NPT
                 + n0 + wv*32 + nt*16 + l15] = v;
        }
      __syncthreads();
    }
  }
}

extern "C" void kernel_launch(void* const* d_in, const int* in_sizes, int n_in,
                              void* d_out, int out_size, void* d_ws, size_t ws_size,
                              hipStream_t stream) {
  const float* x     = (const float*)d_in[0];
  const float* xyz   = (const float*)d_in[1];
  const float* Wq    = (const float*)d_in[2];
  const float* Wkv   = (const float*)d_in[3];
  const float* Wproj = (const float*)d_in[4];
  const float* rp_w1 = (const float*)d_in[5];
  const float* rp_g  = (const float*)d_in[6];
  const float* rp_b  = (const float*)d_in[7];
  const float* rp_m  = (const float*)d_in[8];
  const float* rp_v  = (const float*)d_in[9];
  const float* rp_w2 = (const float*)d_in[10];
  const float* bn1_g = (const float*)d_in[11];
  const float* bn1_b = (const float*)d_in[12];
  const float* bn1_m = (const float*)d_in[13];
  const float* bn1_v = (const float*)d_in[14];
  const float* bn2_g = (const float*)d_in[15];
  const float* bn2_b = (const float*)d_in[16];
  const float* bn2_m = (const float*)d_in[17];
  const float* bn2_v = (const float*)d_in[18];
  const float* ffn_w1 = (const float*)d_in[19];
  const float* ffn_b1 = (const float*)d_in[20];
  const float* ffn_w2 = (const float*)d_in[21];
  const float* ffn_b2 = (const float*)d_in[22];

  char* ws = (char*)d_ws;
  // static region
  float4* w1f = (float4*)(ws + 0);                         //   4 KB
  float4* W2t = (float4*)(ws + 4096);                      //   4 KB
  int*    idx = (int*)  (ws + 8192);                       // 512 KB
  // reuse region A (32 MB): KNN scratch first, then post-attn tensors
  const size_t oA = 532480;
  float4*         Pp     = (float4*)(ws + oA);             // 32 MB [B*N][512] (d,idx)
  unsigned short* attn_b = (unsigned short*)(ws + oA);                 //  4 MB bf16 [B][N][256]
  float*          x1f    = (float*)(ws + oA + (4u<<20));               //  8 MB fp32 [B][N][256]
  unsigned short* x1b    = (unsigned short*)(ws + oA + (12u<<20));     //  4 MB bf16 [B][N][256]
  unsigned short* h_b    = (unsigned short*)(ws + oA + (16u<<20));     // 16 MB bf16 [B][N][1024]
  // region B: weights + casted x + qkv + bias
  const size_t oB = oA + (32u<<20);
  unsigned short* Wqkv_b  = (unsigned short*)(ws + oB);                // 384 KB [768][256]
  unsigned short* Wproj_b = (unsigned short*)(ws + oB + 393216);       // 128 KB
  unsigned short* W1_b    = (unsigned short*)(ws + oB + 524288);       // 512 KB
  unsigned short* W2_b    = (unsigned short*)(ws + oB + 1048576);      // 512 KB
  unsigned short* xb      = (unsigned short*)(ws + oB + 1572864);      //   4 MB bf16 [B][N][256]
  float*          xf      = (float*)(ws + oB + 1572864 + (4u<<20));    //   8 MB fp32 [B][N][256]
  unsigned short* qkv     = (unsigned short*)(ws + oB + 1572864 + (12u<<20)); // 12 MB bf16 [B][N][768]
  float*          biasB   = (float*)(ws + oB + 1572864 + (24u<<20));   //   2 MB [B][N][16][4]

  prep_kernel<<<1, 256, 0, stream>>>(rp_w1, rp_g, rp_b, rp_m, rp_v, rp_w2, w1f, W2t);
  wcast_kernel<<<3072, 256, 0, stream>>>(Wq, Wkv, Wproj, ffn_w1, ffn_w2,
                                         Wqkv_b, Wproj_b, W1_b, W2_b);
  xcast_kernel<<<dim3(64, 4, BB), 256, 0, stream>>>(x, xb, xf);

  knn_partial_kernel<<<dim3(8, 64, BB), 256, 0, stream>>>(xyz, Pp);
  knn_merge_kernel<<<(BB*NPT)/4, 256, 0, stream>>>(Pp, idx);

  MG pqkv = {xb, Wqkv_b, 256, 768, qkv, nullptr,
             nullptr, nullptr, nullptr, nullptr, nullptr, nullptr};
  mgemm_kernel<0><<<dim3(32, 12, BB), 256, 0, stream>>>(pqkv);

  bias_kernel<<<(BB*NPT*KNN)/256, 256, 0, stream>>>(xyz, idx, w1f, W2t, (float4*)biasB);
  attn_kernel<<<BB*NPT, 256, 0, stream>>>(qkv, biasB, idx, attn_b);

  MG pproj = {attn_b, Wproj_b, 256, 256, x1b, x1f,
              nullptr, xf, bn1_g, bn1_b, bn1_m, bn1_v};
  mgemm_kernel<2><<<dim3(32, 4, BB), 256, 0, stream>>>(pproj);

  MG pf1 = {x1b, W1_b, 256, 1024, h_b, nullptr,
            ffn_b1, nullptr, nullptr, nullptr, nullptr, nullptr};
  mgemm_kernel<1><<<dim3(32, 16, BB), 256, 0, stream>>>(pf1);

  MG pf2 = {h_b, W2_b, 1024, 256, nullptr, (float*)d_out,
            ffn_b2, x1f, bn2_g, bn2_b, bn2_m, bn2_v};
  mgemm_kernel<3><<<dim3(32, 4, BB), 256, 0, stream>>>(pf2);
}

// Round 6
// 330.471 us; speedup vs baseline: 4.2350x; 1.0731x over previous
//
#include <hip/hip_runtime.h>
#include <math.h>

#define BB   2
#define CC   256
#define NPT  4096
#define HH   4
#define DD   64
#define KNN  16
#define EPSBN 1e-5f

typedef __attribute__((ext_vector_type(8))) short short8;
typedef __attribute__((ext_vector_type(4))) float f32x4;

__device__ __forceinline__ unsigned short f2b(float f) {
  union { float f; unsigned int u; } v; v.f = f;
  unsigned int r = (v.u + 0x7FFFu + ((v.u >> 16) & 1u)) >> 16;
  return (unsigned short)r;
}
__device__ __forceinline__ float b2f(unsigned short h) {
  union { unsigned int u; float f; } v; v.u = ((unsigned int)h) << 16;
  return v.f;
}

// ---------------- prep: fold rp BN into w1, reduce rp_w2 over heads ----------------
__global__ __launch_bounds__(256)
void prep_kernel(const float* __restrict__ rp_w1, const float* __restrict__ rp_g,
                 const float* __restrict__ rp_b,  const float* __restrict__ rp_m,
                 const float* __restrict__ rp_v,  const float* __restrict__ rp_w2,
                 float4* __restrict__ w1f, float4* __restrict__ W2t) {
  int c = threadIdx.x;
  float s  = rp_g[c] / sqrtf(rp_v[c] + EPSBN);
  float b0 = rp_b[c] - rp_m[c] * s;
  w1f[c] = make_float4(rp_w1[c*3+0]*s, rp_w1[c*3+1]*s, rp_w1[c*3+2]*s, b0);
  float a0=0.f,a1=0.f,a2=0.f,a3=0.f;
  for (int o = 0; o < 64; o++) {
    a0 += rp_w2[(      o)*CC + c];
    a1 += rp_w2[( 64 + o)*CC + c];
    a2 += rp_w2[(128 + o)*CC + c];
    a3 += rp_w2[(192 + o)*CC + c];
  }
  W2t[c] = make_float4(a0,a1,a2,a3);
}

// ---------------- cast weights to bf16 (qkv rows concatenated [Wq;Wkv]) ------------
__global__ __launch_bounds__(256)
void wcast_kernel(const float* __restrict__ Wq, const float* __restrict__ Wkv,
                  const float* __restrict__ Wp, const float* __restrict__ W1,
                  const float* __restrict__ W2,
                  unsigned short* __restrict__ oQKV, unsigned short* __restrict__ oP,
                  unsigned short* __restrict__ o1,   unsigned short* __restrict__ o2) {
  int i = blockIdx.x * 256 + threadIdx.x;          // 786432 total
  if (i < 65536)        oQKV[i] = f2b(Wq[i]);
  else if (i < 196608)  oQKV[i] = f2b(Wkv[i - 65536]);
  else if (i < 262144)  oP[i - 196608] = f2b(Wp[i - 196608]);
  else if (i < 524288)  o1[i - 262144] = f2b(W1[i - 262144]);
  else                  o2[i - 524288] = f2b(W2[i - 524288]);
}

// ---------------- transpose+cast x: [B][C][N] fp32 -> [B][N][C] bf16 + fp32 --------
__global__ __launch_bounds__(256)
void xcast_kernel(const float* __restrict__ x, unsigned short* __restrict__ xb,
                  float* __restrict__ xf) {
  __shared__ float T[64][65];
  int n0 = blockIdx.x * 64, c0 = blockIdx.y * 64, bb = blockIdx.z;
  int tid = threadIdx.x;
  {
    int crow = tid >> 2, ns = (tid & 3) * 16;
    const float* xp = x + ((size_t)(bb*CC + c0 + crow))*NPT + n0 + ns;
#pragma unroll
    for (int i = 0; i < 4; i++) {
      float4 v = ((const float4*)xp)[i];
      T[crow][ns + i*4 + 0] = v.x; T[crow][ns + i*4 + 1] = v.y;
      T[crow][ns + i*4 + 2] = v.z; T[crow][ns + i*4 + 3] = v.w;
    }
  }
  __syncthreads();
  {
    int nrow = tid >> 2, cs = (tid & 3) * 16;
    float vals[16];
#pragma unroll
    for (int i = 0; i < 16; i++) vals[i] = T[cs + i][nrow];
    size_t orow = ((size_t)(bb*NPT + n0 + nrow))*CC + c0 + cs;
#pragma unroll
    for (int i = 0; i < 4; i++)
      *(float4*)&xf[orow + i*4] = make_float4(vals[i*4], vals[i*4+1], vals[i*4+2], vals[i*4+3]);
    unsigned short us[16];
#pragma unroll
    for (int i = 0; i < 16; i++) us[i] = f2b(vals[i]);
    *(uint4*)&xb[orow]     = *(const uint4*)&us[0];
    *(uint4*)&xb[orow + 8] = *(const uint4*)&us[8];
  }
}

// ---------------- KNN stage 1: branch-free sorted insert, f32 dist + i32 idx -------
// Separate 32-bit arrays keep the lists in VGPRs (u64 keys got shuttled through
// AGPRs -> 2.3x instruction bloat, R5 post-mortem). Strict < on dist + ascending
// candidate scan reproduces lax.top_k's lower-idx-on-tie semantics.
__global__ __launch_bounds__(256)
void knn_partial_kernel(const float* __restrict__ xyz, float4* __restrict__ Pp) {
  __shared__ float sx[512], sy[512], sz[512], sw[512];
  int s  = blockIdx.x;          // candidate slice 0..7
  int qg = blockIdx.y;          // query group 0..63
  int b  = blockIdx.z;
  const float* base = xyz + (size_t)b * 3 * NPT;
  int c0 = s * 512;
  for (int i = threadIdx.x; i < 512; i += 256) {
    float mx = base[c0 + i], my = base[NPT + c0 + i], mz = base[2*NPT + c0 + i];
    sx[i] = mx; sy[i] = my; sz[i] = mz;
    sw[i] = mx*mx + my*my + mz*mz;
  }
  int lane = threadIdx.x & 63;
  int wv   = threadIdx.x >> 6;
  int qn   = qg * 64 + lane;
  float qx = base[qn], qy = base[NPT + qn], qz = base[2*NPT + qn];
  float qsq = qx*qx + qy*qy + qz*qz;
  float qx2 = -2.f*qx, qy2 = -2.f*qy, qz2 = -2.f*qz;
  __syncthreads();

  float kd[16]; int ki[16];
#pragma unroll
  for (int t = 0; t < 16; t++) { kd[t] = 3.4e38f; ki[t] = 0x7fffffff; }

  int mbase = wv * 128;
#pragma unroll 2
  for (int mm = 0; mm < 128; mm++) {
    int m = mbase + mm;
    float nd = fmaf(qx2, sx[m], fmaf(qy2, sy[m], fmaf(qz2, sz[m], sw[m] + qsq)));
    int   ni = c0 + m;
#pragma unroll
    for (int t = 0; t < 16; t++) {
      bool c = nd < kd[t];
      float dlo = c ? nd : kd[t];
      int   ilo = c ? ni : ki[t];
      nd = c ? kd[t] : nd;
      ni = c ? ki[t] : ni;
      kd[t] = dlo; ki[t] = ilo;
    }
  }

  int gq = b * NPT + qn;
  float4* out = Pp + (size_t)gq * 256 + (s*4 + wv)*8;   // 128B contiguous per thread
#pragma unroll
  for (int t = 0; t < 8; t++)
    out[t] = make_float4(kd[2*t], __int_as_float(ki[2*t]),
                         kd[2*t+1], __int_as_float(ki[2*t+1]));
}

// ---------------- KNN stage 2: one WAVE per query, 8 entries/lane, 16 select-min rounds ----
__global__ __launch_bounds__(256)
void knn_merge_kernel(const float4* __restrict__ Pp, int* __restrict__ idx_out) {
  int wv   = threadIdx.x >> 6;
  int lane = threadIdx.x & 63;
  int gq   = blockIdx.x * 4 + wv;
  float d[8]; int ii[8];
  const float4* base = Pp + (size_t)gq * 256;
#pragma unroll
  for (int j = 0; j < 4; j++) {
    float4 v = base[j*64 + lane];
    d[2*j+0] = v.x; ii[2*j+0] = __float_as_int(v.y);
    d[2*j+1] = v.z; ii[2*j+1] = __float_as_int(v.w);
  }
  for (int sel = 0; sel < 16; sel++) {
    float bd = 3.5e38f; int bi = 0x7fffffff;
#pragma unroll
    for (int t = 0; t < 8; t++) {
      bool better = (d[t] < bd) || (d[t] == bd && ii[t] < bi);
      if (better) { bd = d[t]; bi = ii[t]; }
    }
#pragma unroll
    for (int off = 1; off < 64; off <<= 1) {
      float od = __shfl_xor(bd, off, 64);
      int   oi = __shfl_xor(bi, off, 64);
      if (od < bd || (od == bd && oi < bi)) { bd = od; bi = oi; }
    }
#pragma unroll
    for (int t = 0; t < 8; t++)
      if (ii[t] == bi) d[t] = 3.5e38f;
    if (lane == 0) idx_out[gq*16 + sel] = bi;
  }
}

// ---------------- fused rel-pos bias (unchanged) ----------------
__global__ __launch_bounds__(256)
void bias_kernel(const float* __restrict__ xyz, const int* __restrict__ idx,
                 const float4* __restrict__ w1f, const float4* __restrict__ W2t,
                 float4* __restrict__ biasB) {
  __shared__ float4 sw1[256];
  __shared__ float4 sw2[256];
  int tid = threadIdx.x;
  sw1[tid] = w1f[tid];
  sw2[tid] = W2t[tid];
  __syncthreads();
  int gid = blockIdx.x * 256 + tid;
  int b = gid >> 16;
  int n = (gid >> 4) & 4095;
  int j = idx[gid];
  const float* base = xyz + (size_t)b * 3 * NPT;
  float rx = base[j]         - base[n];
  float ry = base[NPT + j]   - base[NPT + n];
  float rz = base[2*NPT + j] - base[2*NPT + n];
  float a0=0.f,a1=0.f,a2=0.f,a3=0.f;
#pragma unroll 8
  for (int c = 0; c < 256; c++) {
    float4 w = sw1[c];
    float t = fmaf(rx, w.x, fmaf(ry, w.y, fmaf(rz, w.z, w.w)));
    t = fmaxf(t, 0.f);
    float4 w2 = sw2[c];
    a0 = fmaf(t, w2.x, a0); a1 = fmaf(t, w2.y, a1);
    a2 = fmaf(t, w2.z, a2); a3 = fmaf(t, w2.w, a3);
  }
  biasB[gid] = make_float4(a0,a1,a2,a3);
}

// ---------------- fused attention: qkv bf16 [B][N][768]; out bf16 [B][N][256] -------
__global__ __launch_bounds__(256)
void attn_kernel(const unsigned short* __restrict__ qkv, const float* __restrict__ biasB,
                 const int* __restrict__ idx, unsigned short* __restrict__ attn_b) {
  int bn = blockIdx.x;
  int b  = bn >> 12;
  __shared__ int sidx[16];
  if (threadIdx.x < 16) sidx[threadIdx.x] = idx[bn*16 + threadIdx.x];
  __syncthreads();
  int wv = threadIdx.x >> 6;
  int c  = threadIdx.x;
  float qv = b2f(qkv[(size_t)bn*768 + c]) * 0.125f;
  size_t base = (size_t)(b*NPT) * 768;
  float part[16];
#pragma unroll
  for (int k = 0; k < 16; k++) {
    int j = sidx[k];
    part[k] = qv * b2f(qkv[base + (size_t)j*768 + 256 + c]);
  }
#pragma unroll
  for (int off = 32; off > 0; off >>= 1) {
#pragma unroll
    for (int k = 0; k < 16; k++) part[k] += __shfl_xor(part[k], off, 64);
  }
  float mx = -3.4e38f;
#pragma unroll
  for (int k = 0; k < 16; k++) {
    part[k] += biasB[(size_t)(bn*16 + k)*4 + wv];
    mx = fmaxf(mx, part[k]);
  }
  float s = 0.f;
#pragma unroll
  for (int k = 0; k < 16; k++) { part[k] = __expf(part[k] - mx); s += part[k]; }
  float inv = 1.f / s;
  float o = 0.f;
#pragma unroll
  for (int k = 0; k < 16; k++) {
    int j = sidx[k];
    o = fmaf(part[k], b2f(qkv[base + (size_t)j*768 + 512 + c]), o);
  }
  attn_b[(size_t)bn*256 + c] = f2b(o * inv);
}

// ---------------- MFMA bf16 GEMM: D[n][m] = A[n][k] * W[m][k] ----------------
struct MG {
  const unsigned short* A; const unsigned short* Wt; int K; int M;
  unsigned short* OutB; float* OutF;
  const float* bias; const float* resid;
  const float* bng; const float* bnb; const float* bnm; const float* bnv;
};

template<int EPI>
__global__ __launch_bounds__(256)
void mgemm_kernel(MG p) {
  __shared__ unsigned short As[128][40];
  __shared__ unsigned short Bs[64][40];
  const int tid  = threadIdx.x;
  const int bb   = blockIdx.z;
  const int n0   = blockIdx.x * 128;
  const int m0   = blockIdx.y * 64;
  const int lane = tid & 63;
  const int wv   = tid >> 6;
  const int l15  = lane & 15;
  const int quad = lane >> 4;
  const int K    = p.K;

  f32x4 acc[2][4];
#pragma unroll
  for (int i = 0; i < 2; i++)
#pragma unroll
    for (int j = 0; j < 4; j++) acc[i][j] = (f32x4){0.f, 0.f, 0.f, 0.f};

  const int arow = tid >> 1, ahalf = tid & 1;
  const int wrow = tid >> 2, wseg = tid & 3;
  const unsigned short* Ap = p.A  + (size_t)(bb*NPT + n0 + arow)*K + ahalf*16;
  const unsigned short* Wp = p.Wt + (size_t)(m0 + wrow)*K + wseg*8;

  for (int c0 = 0; c0 < K; c0 += 32) {
    uint4 va0 = *(const uint4*)(Ap + c0);
    uint4 va1 = *(const uint4*)(Ap + c0 + 8);
    uint4 vw  = *(const uint4*)(Wp + c0);
    *(uint4*)&As[arow][ahalf*16]     = va0;
    *(uint4*)&As[arow][ahalf*16 + 8] = va1;
    *(uint4*)&Bs[wrow][wseg*8]       = vw;
    __syncthreads();
    short8 bf[4];
#pragma unroll
    for (int mt = 0; mt < 4; mt++)
      bf[mt] = *(const short8*)&Bs[mt*16 + l15][quad*8];
#pragma unroll
    for (int nt = 0; nt < 2; nt++) {
      short8 af = *(const short8*)&As[wv*32 + nt*16 + l15][quad*8];
#pragma unroll
      for (int mt = 0; mt < 4; mt++)
        acc[nt][mt] = __builtin_amdgcn_mfma_f32_16x16x32_bf16(af, bf[mt], acc[nt][mt], 0, 0, 0);
    }
    __syncthreads();
  }

  if (EPI == 0 || EPI == 1) {
    float bs[4];
#pragma unroll
    for (int mt = 0; mt < 4; mt++)
      bs[mt] = (EPI == 1) ? p.bias[m0 + mt*16 + l15] : 0.f;
#pragma unroll
    for (int nt = 0; nt < 2; nt++)
#pragma unroll
      for (int reg = 0; reg < 4; reg++) {
        size_t row = ((size_t)(bb*NPT + n0 + wv*32 + nt*16 + quad*4 + reg))*p.M + m0;
#pragma unroll
        for (int mt = 0; mt < 4; mt++) {
          float v = acc[nt][mt][reg] + bs[mt];
          if (EPI == 1) v = fmaxf(v, 0.f);
          p.OutB[row + mt*16 + l15] = f2b(v);
        }
      }
  } else if (EPI == 2) {
    float sc[4], sh[4];
#pragma unroll
    for (int mt = 0; mt < 4; mt++) {
      int m = m0 + mt*16 + l15;
      float s = p.bng[m] / sqrtf(p.bnv[m] + EPSBN);
      sc[mt] = s; sh[mt] = p.bnb[m] - p.bnm[m]*s;
    }
#pragma unroll
    for (int nt = 0; nt < 2; nt++)
#pragma unroll
      for (int reg = 0; reg < 4; reg++) {
        size_t row = ((size_t)(bb*NPT + n0 + wv*32 + nt*16 + quad*4 + reg))*p.M + m0;
#pragma unroll
        for (int mt = 0; mt < 4; mt++) {
          float r = p.resid[row + mt*16 + l15];
          float v = (acc[nt][mt][reg] + r)*sc[mt] + sh[mt];
          p.OutF[row + mt*16 + l15] = v;
          p.OutB[row + mt*16 + l15] = f2b(v);
        }
      }
  } else {  // EPI == 3
    __shared__ float Tb[4][4][16*17];
    float sc[4], sh[4], bs[4];
#pragma unroll
    for (int mt = 0; mt < 4; mt++) {
      int m = m0 + mt*16 + l15;
      float s = p.bng[m] / sqrtf(p.bnv[m] + EPSBN);
      sc[mt] = s; sh[mt] = p.bnb[m] - p.bnm[m]*s;
      bs[mt] = p.bias[m];
    }
#pragma unroll
    for (int nt = 0; nt < 2; nt++) {
#pragma unroll
      for (int reg = 0; reg < 4; reg++) {
        size_t row = ((size_t)(bb*NPT + n0 + wv*32 + nt*16 + quad*4 + reg))*p.M + m0;
#pragma unroll
        for (int mt = 0; mt < 4; mt++) {
          float r = p.resid[row + mt*16 + l15];
          float v = (acc[nt][mt][reg] + bs[mt] + r)*sc[mt] + sh[mt];
          Tb[wv][mt][(quad*4 + reg)*17 + l15] = v;
        }
      }
      __syncthreads();
#pragma unroll
      for (int mt = 0; mt < 4; mt++)
#pragma unroll
        for (int reg = 0; reg < 4; reg++) {
          float v = Tb[wv][mt][l15*17 + quad*4 + reg];
          p.OutF[((size_t)(bb*p.M + m0 + mt*16 + quad*4 + reg))*NPT
                 + n0 + wv*32 + nt*16 + l15] = v;
        }
      __syncthreads();
    }
  }
}

extern "C" void kernel_launch(void* const* d_in, const int* in_sizes, int n_in,
                              void* d_out, int out_size, void* d_ws, size_t ws_size,
                              hipStream_t stream) {
  const float* x     = (const float*)d_in[0];
  const float* xyz   = (const float*)d_in[1];
  const float* Wq    = (const float*)d_in[2];
  const float* Wkv   = (const float*)d_in[3];
  const float* Wproj = (const float*)d_in[4];
  const float* rp_w1 = (const float*)d_in[5];
  const float* rp_g  = (const float*)d_in[6];
  const float* rp_b  = (const float*)d_in[7];
  const float* rp_m  = (const float*)d_in[8];
  const float* rp_v  = (const float*)d_in[9];
  const float* rp_w2 = (const float*)d_in[10];
  const float* bn1_g = (const float*)d_in[11];
  const float* bn1_b = (const float*)d_in[12];
  const float* bn1_m = (const float*)d_in[13];
  const float* bn1_v = (const float*)d_in[14];
  const float* bn2_g = (const float*)d_in[15];
  const float* bn2_b = (const float*)d_in[16];
  const float* bn2_m = (const float*)d_in[17];
  const float* bn2_v = (const float*)d_in[18];
  const float* ffn_w1 = (const float*)d_in[19];
  const float* ffn_b1 = (const float*)d_in[20];
  const float* ffn_w2 = (const float*)d_in[21];
  const float* ffn_b2 = (const float*)d_in[22];

  char* ws = (char*)d_ws;
  // static region
  float4* w1f = (float4*)(ws + 0);                         //   4 KB
  float4* W2t = (float4*)(ws + 4096);                      //   4 KB
  int*    idx = (int*)  (ws + 8192);                       // 512 KB
  // reuse region A (32 MB): KNN scratch first, then post-attn tensors
  const size_t oA = 532480;
  float4*         Pp     = (float4*)(ws + oA);             // 32 MB [B*N][512] (d,idx)
  unsigned short* attn_b = (unsigned short*)(ws + oA);                 //  4 MB bf16 [B][N][256]
  float*          x1f    = (float*)(ws + oA + (4u<<20));               //  8 MB fp32 [B][N][256]
  unsigned short* x1b    = (unsigned short*)(ws + oA + (12u<<20));     //  4 MB bf16 [B][N][256]
  unsigned short* h_b    = (unsigned short*)(ws + oA + (16u<<20));     // 16 MB bf16 [B][N][1024]
  // region B: weights + casted x + qkv + bias
  const size_t oB = oA + (32u<<20);
  unsigned short* Wqkv_b  = (unsigned short*)(ws + oB);                // 384 KB [768][256]
  unsigned short* Wproj_b = (unsigned short*)(ws + oB + 393216);       // 128 KB
  unsigned short* W1_b    = (unsigned short*)(ws + oB + 524288);       // 512 KB
  unsigned short* W2_b    = (unsigned short*)(ws + oB + 1048576);      // 512 KB
  unsigned short* xb      = (unsigned short*)(ws + oB + 1572864);      //   4 MB bf16 [B][N][256]
  float*          xf      = (float*)(ws + oB + 1572864 + (4u<<20));    //   8 MB fp32 [B][N][256]
  unsigned short* qkv     = (unsigned short*)(ws + oB + 1572864 + (12u<<20)); // 12 MB bf16 [B][N][768]
  float*          biasB   = (float*)(ws + oB + 1572864 + (24u<<20));   //   2 MB [B][N][16][4]

  prep_kernel<<<1, 256, 0, stream>>>(rp_w1, rp_g, rp_b, rp_m, rp_v, rp_w2, w1f, W2t);
  wcast_kernel<<<3072, 256, 0, stream>>>(Wq, Wkv, Wproj, ffn_w1, ffn_w2,
                                         Wqkv_b, Wproj_b, W1_b, W2_b);
  xcast_kernel<<<dim3(64, 4, BB), 256, 0, stream>>>(x, xb, xf);

  knn_partial_kernel<<<dim3(8, 64, BB), 256, 0, stream>>>(xyz, Pp);
  knn_merge_kernel<<<(BB*NPT)/4, 256, 0, stream>>>(Pp, idx);

  MG pqkv = {xb, Wqkv_b, 256, 768, qkv, nullptr,
             nullptr, nullptr, nullptr, nullptr, nullptr, nullptr};
  mgemm_kernel<0><<<dim3(32, 12, BB), 256, 0, stream>>>(pqkv);

  bias_kernel<<<(BB*NPT*KNN)/256, 256, 0, stream>>>(xyz, idx, w1f, W2t, (float4*)biasB);
  attn_kernel<<<BB*NPT, 256, 0, stream>>>(qkv, biasB, idx, attn_b);

  MG pproj = {attn_b, Wproj_b, 256, 256, x1b, x1f,
              nullptr, xf, bn1_g, bn1_b, bn1_m, bn1_v};
  mgemm_kernel<2><<<dim3(32, 4, BB), 256, 0, stream>>>(pproj);

  MG pf1 = {x1b, W1_b, 256, 1024, h_b, nullptr,
            ffn_b1, nullptr, nullptr, nullptr, nullptr, nullptr};
  mgemm_kernel<1><<<dim3(32, 16, BB), 256, 0, stream>>>(pf1);

  MG pf2 = {h_b, W2_b, 1024, 256, nullptr, (float*)d_out,
            ffn_b2, x1f, bn2_g, bn2_b, bn2_m, bn2_v};
  mgemm_kernel<3><<<dim3(32, 4, BB), 256, 0, stream>>>(pf2);
}

// Round 7
// 312.362 us; speedup vs baseline: 4.4805x; 1.0580x over previous
//
#include <hip/hip_runtime.h>
#include <math.h>

#define BB   2
#define CC   256
#define NPT  4096
#define HH   4
#define DD   64
#define KNN  16
#define EPSBN 1e-5f

typedef __attribute__((ext_vector_type(8))) short short8;
typedef __attribute__((ext_vector_type(4))) float f32x4;

__device__ __forceinline__ unsigned short f2b(float f) {
  union { float f; unsigned int u; } v; v.f = f;
  unsigned int r = (v.u + 0x7FFFu + ((v.u >> 16) & 1u)) >> 16;
  return (unsigned short)r;
}
__device__ __forceinline__ float b2f(unsigned short h) {
  union { unsigned int u; float f; } v; v.u = ((unsigned int)h) << 16;
  return v.f;
}
__device__ __forceinline__ void up2(unsigned int u, float& a, float& b) {
  union { unsigned int x; float f; } lo, hi;
  lo.x = u << 16; hi.x = u & 0xffff0000u;
  a = lo.f; b = hi.f;
}
__device__ __forceinline__ void up16(uint4 u0, uint4 u1, float* f) {
  up2(u0.x, f[0], f[1]);  up2(u0.y, f[2], f[3]);
  up2(u0.z, f[4], f[5]);  up2(u0.w, f[6], f[7]);
  up2(u1.x, f[8], f[9]);  up2(u1.y, f[10], f[11]);
  up2(u1.z, f[12], f[13]); up2(u1.w, f[14], f[15]);
}

// ---------------- prep: fold rp BN into w1, reduce rp_w2 over heads ----------------
__global__ __launch_bounds__(256)
void prep_kernel(const float* __restrict__ rp_w1, const float* __restrict__ rp_g,
                 const float* __restrict__ rp_b,  const float* __restrict__ rp_m,
                 const float* __restrict__ rp_v,  const float* __restrict__ rp_w2,
                 float4* __restrict__ w1f, float4* __restrict__ W2t) {
  int c = threadIdx.x;
  float s  = rp_g[c] / sqrtf(rp_v[c] + EPSBN);
  float b0 = rp_b[c] - rp_m[c] * s;
  w1f[c] = make_float4(rp_w1[c*3+0]*s, rp_w1[c*3+1]*s, rp_w1[c*3+2]*s, b0);
  float a0=0.f,a1=0.f,a2=0.f,a3=0.f;
  for (int o = 0; o < 64; o++) {
    a0 += rp_w2[(      o)*CC + c];
    a1 += rp_w2[( 64 + o)*CC + c];
    a2 += rp_w2[(128 + o)*CC + c];
    a3 += rp_w2[(192 + o)*CC + c];
  }
  W2t[c] = make_float4(a0,a1,a2,a3);
}

// ---------------- cast weights to bf16 (qkv rows concatenated [Wq;Wkv]) ------------
__global__ __launch_bounds__(256)
void wcast_kernel(const float* __restrict__ Wq, const float* __restrict__ Wkv,
                  const float* __restrict__ Wp, const float* __restrict__ W1,
                  const float* __restrict__ W2,
                  unsigned short* __restrict__ oQKV, unsigned short* __restrict__ oP,
                  unsigned short* __restrict__ o1,   unsigned short* __restrict__ o2) {
  int i = blockIdx.x * 256 + threadIdx.x;          // 786432 total
  if (i < 65536)        oQKV[i] = f2b(Wq[i]);
  else if (i < 196608)  oQKV[i] = f2b(Wkv[i - 65536]);
  else if (i < 262144)  oP[i - 196608] = f2b(Wp[i - 196608]);
  else if (i < 524288)  o1[i - 262144] = f2b(W1[i - 262144]);
  else                  o2[i - 524288] = f2b(W2[i - 524288]);
}

// ---------------- transpose+cast x: [B][C][N] fp32 -> [B][N][C] bf16 + fp32 --------
__global__ __launch_bounds__(256)
void xcast_kernel(const float* __restrict__ x, unsigned short* __restrict__ xb,
                  float* __restrict__ xf) {
  __shared__ float T[64][65];
  int n0 = blockIdx.x * 64, c0 = blockIdx.y * 64, bb = blockIdx.z;
  int tid = threadIdx.x;
  {
    int crow = tid >> 2, ns = (tid & 3) * 16;
    const float* xp = x + ((size_t)(bb*CC + c0 + crow))*NPT + n0 + ns;
#pragma unroll
    for (int i = 0; i < 4; i++) {
      float4 v = ((const float4*)xp)[i];
      T[crow][ns + i*4 + 0] = v.x; T[crow][ns + i*4 + 1] = v.y;
      T[crow][ns + i*4 + 2] = v.z; T[crow][ns + i*4 + 3] = v.w;
    }
  }
  __syncthreads();
  {
    int nrow = tid >> 2, cs = (tid & 3) * 16;
    float vals[16];
#pragma unroll
    for (int i = 0; i < 16; i++) vals[i] = T[cs + i][nrow];
    size_t orow = ((size_t)(bb*NPT + n0 + nrow))*CC + c0 + cs;
#pragma unroll
    for (int i = 0; i < 4; i++)
      *(float4*)&xf[orow + i*4] = make_float4(vals[i*4], vals[i*4+1], vals[i*4+2], vals[i*4+3]);
    unsigned short us[16];
#pragma unroll
    for (int i = 0; i < 16; i++) us[i] = f2b(vals[i]);
    *(uint4*)&xb[orow]     = *(const uint4*)&us[0];
    *(uint4*)&xb[orow + 8] = *(const uint4*)&us[8];
  }
}

// ---------------- KNN stage 1: branch-free sorted insert, f32 dist + i32 idx -------
// __launch_bounds__(256,4): cap occupancy target at 4 waves/EU so the 32-register
// (kd,ki) lists stay in VGPRs. Default allocation chose 28 VGPRs and shuttled the
// lists through AGPRs (~75 extra v_accvgpr ops/candidate — R5/R6 post-mortem).
__global__ __launch_bounds__(256, 4)
void knn_partial_kernel(const float* __restrict__ xyz, float4* __restrict__ Pp) {
  __shared__ float4 sp[512];    // (x, y, z, |p|^2)
  int s  = blockIdx.x;          // candidate slice 0..7
  int qg = blockIdx.y;          // query group 0..63
  int b  = blockIdx.z;
  const float* base = xyz + (size_t)b * 3 * NPT;
  int c0 = s * 512;
  for (int i = threadIdx.x; i < 512; i += 256) {
    float mx = base[c0 + i], my = base[NPT + c0 + i], mz = base[2*NPT + c0 + i];
    sp[i] = make_float4(mx, my, mz, mx*mx + my*my + mz*mz);
  }
  int lane = threadIdx.x & 63;
  int wv   = threadIdx.x >> 6;
  int qn   = qg * 64 + lane;
  float qx = base[qn], qy = base[NPT + qn], qz = base[2*NPT + qn];
  float qsq = qx*qx + qy*qy + qz*qz;
  float qx2 = -2.f*qx, qy2 = -2.f*qy, qz2 = -2.f*qz;
  __syncthreads();

  float kd[16]; int ki[16];
#pragma unroll
  for (int t = 0; t < 16; t++) { kd[t] = 3.4e38f; ki[t] = 0x7fffffff; }

  int mbase = wv * 128;
#pragma unroll 2
  for (int mm = 0; mm < 128; mm++) {
    int m = mbase + mm;
    float4 m4 = sp[m];                       // broadcast read, conflict-free
    float nd = fmaf(qx2, m4.x, fmaf(qy2, m4.y, fmaf(qz2, m4.z, m4.w + qsq)));
    int   ni = c0 + m;
#pragma unroll
    for (int t = 0; t < 16; t++) {
      bool c = nd < kd[t];
      float dlo = c ? nd : kd[t];
      int   ilo = c ? ni : ki[t];
      nd = c ? kd[t] : nd;
      ni = c ? ki[t] : ni;
      kd[t] = dlo; ki[t] = ilo;
    }
  }

  int gq = b * NPT + qn;
  float4* out = Pp + (size_t)gq * 256 + (s*4 + wv)*8;   // 128B contiguous per thread
#pragma unroll
  for (int t = 0; t < 8; t++)
    out[t] = make_float4(kd[2*t], __int_as_float(ki[2*t]),
                         kd[2*t+1], __int_as_float(ki[2*t+1]));
}

// ---------------- KNN stage 2: one WAVE per query, 8 entries/lane, 16 select-min rounds ----
__global__ __launch_bounds__(256)
void knn_merge_kernel(const float4* __restrict__ Pp, int* __restrict__ idx_out) {
  int wv   = threadIdx.x >> 6;
  int lane = threadIdx.x & 63;
  int gq   = blockIdx.x * 4 + wv;
  float d[8]; int ii[8];
  const float4* base = Pp + (size_t)gq * 256;
#pragma unroll
  for (int j = 0; j < 4; j++) {
    float4 v = base[j*64 + lane];
    d[2*j+0] = v.x; ii[2*j+0] = __float_as_int(v.y);
    d[2*j+1] = v.z; ii[2*j+1] = __float_as_int(v.w);
  }
  for (int sel = 0; sel < 16; sel++) {
    float bd = 3.5e38f; int bi = 0x7fffffff;
#pragma unroll
    for (int t = 0; t < 8; t++) {
      bool better = (d[t] < bd) || (d[t] == bd && ii[t] < bi);
      if (better) { bd = d[t]; bi = ii[t]; }
    }
#pragma unroll
    for (int off = 1; off < 64; off <<= 1) {
      float od = __shfl_xor(bd, off, 64);
      int   oi = __shfl_xor(bi, off, 64);
      if (od < bd || (od == bd && oi < bi)) { bd = od; bi = oi; }
    }
#pragma unroll
    for (int t = 0; t < 8; t++)
      if (ii[t] == bi) d[t] = 3.5e38f;
    if (lane == 0) idx_out[gq*16 + sel] = bi;
  }
}

// ---------------- fused rel-pos bias (unchanged) ----------------
__global__ __launch_bounds__(256)
void bias_kernel(const float* __restrict__ xyz, const int* __restrict__ idx,
                 const float4* __restrict__ w1f, const float4* __restrict__ W2t,
                 float4* __restrict__ biasB) {
  __shared__ float4 sw1[256];
  __shared__ float4 sw2[256];
  int tid = threadIdx.x;
  sw1[tid] = w1f[tid];
  sw2[tid] = W2t[tid];
  __syncthreads();
  int gid = blockIdx.x * 256 + tid;
  int b = gid >> 16;
  int n = (gid >> 4) & 4095;
  int j = idx[gid];
  const float* base = xyz + (size_t)b * 3 * NPT;
  float rx = base[j]         - base[n];
  float ry = base[NPT + j]   - base[NPT + n];
  float rz = base[2*NPT + j] - base[2*NPT + n];
  float a0=0.f,a1=0.f,a2=0.f,a3=0.f;
#pragma unroll 8
  for (int c = 0; c < 256; c++) {
    float4 w = sw1[c];
    float t = fmaf(rx, w.x, fmaf(ry, w.y, fmaf(rz, w.z, w.w)));
    t = fmaxf(t, 0.f);
    float4 w2 = sw2[c];
    a0 = fmaf(t, w2.x, a0); a1 = fmaf(t, w2.y, a1);
    a2 = fmaf(t, w2.z, a2); a3 = fmaf(t, w2.w, a3);
  }
  biasB[gid] = make_float4(a0,a1,a2,a3);
}

// ---------------- fused attention v2: lane = (neighbor k, 16-ch chunk) -------------
// Dot products contract in-lane over 16 channels (uint4 bf16 loads); cross-lane work
// is 2 shuffles (chunk combine) + 8 shuffles (softmax over k) + one small per-wave
// LDS transpose for the PV channel reduction. Replaces 96 bpermutes/thread of v1.
__global__ __launch_bounds__(256, 4)
void attn_kernel(const unsigned short* __restrict__ qkv, const float* __restrict__ biasB,
                 const int* __restrict__ idx, unsigned short* __restrict__ attn_b) {
  __shared__ int sidx[16];
  __shared__ float red[4][16*68];   // per-wave [k][68] rows, 17408 B total
  int bn = blockIdx.x;
  int b  = bn >> 12;
  if (threadIdx.x < 16) sidx[threadIdx.x] = idx[bn*16 + threadIdx.x];
  __syncthreads();
  int wv   = threadIdx.x >> 6;      // head
  int lane = threadIdx.x & 63;
  int k    = lane >> 2;             // neighbor
  int c4   = lane & 3;              // channel chunk
  int ch0  = wv*64 + c4*16;
  size_t rowq = (size_t)bn * 768;
  size_t base = (size_t)(b*NPT) * 768;

  float qf[16];
  {
    uint4 q0 = *(const uint4*)(qkv + rowq + ch0);
    uint4 q1 = *(const uint4*)(qkv + rowq + ch0 + 8);
    up16(q0, q1, qf);
  }
  int j = sidx[k];
  float dot = 0.f;
  {
    const unsigned short* krow = qkv + base + (size_t)j*768 + 256 + ch0;
    uint4 k0 = *(const uint4*)(krow);
    uint4 k1 = *(const uint4*)(krow + 8);
    float kf[16];
    up16(k0, k1, kf);
#pragma unroll
    for (int i = 0; i < 16; i++) dot = fmaf(qf[i], kf[i], dot);
  }
  dot += __shfl_xor(dot, 1, 64);
  dot += __shfl_xor(dot, 2, 64);
  float logit = dot * 0.125f + biasB[(size_t)(bn*16 + k)*4 + wv];
  float mx = logit;
#pragma unroll
  for (int off = 4; off < 64; off <<= 1) mx = fmaxf(mx, __shfl_xor(mx, off, 64));
  float e = __expf(logit - mx);
  float ssum = e;
#pragma unroll
  for (int off = 4; off < 64; off <<= 1) ssum += __shfl_xor(ssum, off, 64);
  float w = e / ssum;

  // PV: each lane weights its 16 channels of v[k]; transpose-reduce over k via LDS
  {
    const unsigned short* vrow = qkv + base + (size_t)j*768 + 512 + ch0;
    uint4 v0 = *(const uint4*)(vrow);
    uint4 v1 = *(const uint4*)(vrow + 8);
    float vf[16];
    up16(v0, v1, vf);
    float* dst = &red[wv][k*68 + c4*16];
#pragma unroll
    for (int g = 0; g < 4; g++)
      ((float4*)dst)[g] = make_float4(w*vf[g*4], w*vf[g*4+1], w*vf[g*4+2], w*vf[g*4+3]);
  }
  __syncthreads();
  float o = 0.f;
#pragma unroll
  for (int kk = 0; kk < 16; kk++) o += red[wv][kk*68 + lane];   // 2-way = free
  attn_b[(size_t)bn*256 + wv*64 + lane] = f2b(o);
}

// ---------------- MFMA bf16 GEMM: D[n][m] = A[n][k] * W[m][k] ----------------
struct MG {
  const unsigned short* A; const unsigned short* Wt; int K; int M;
  unsigned short* OutB; float* OutF;
  const float* bias; const float* resid;
  const float* bng; const float* bnb; const float* bnm; const float* bnv;
};

template<int EPI>
__global__ __launch_bounds__(256)
void mgemm_kernel(MG p) {
  __shared__ unsigned short As[128][40];
  __shared__ unsigned short Bs[64][40];
  const int tid  = threadIdx.x;
  const int bb   = blockIdx.z;
  const int n0   = blockIdx.x * 128;
  const int m0   = blockIdx.y * 64;
  const int lane = tid & 63;
  const int wv   = tid >> 6;
  const int l15  = lane & 15;
  const int quad = lane >> 4;
  const int K    = p.K;

  f32x4 acc[2][4];
#pragma unroll
  for (int i = 0; i < 2; i++)
#pragma unroll
    for (int j = 0; j < 4; j++) acc[i][j] = (f32x4){0.f, 0.f, 0.f, 0.f};

  const int arow = tid >> 1, ahalf = tid & 1;
  const int wrow = tid >> 2, wseg = tid & 3;
  const unsigned short* Ap = p.A  + (size_t)(bb*NPT + n0 + arow)*K + ahalf*16;
  const unsigned short* Wp = p.Wt + (size_t)(m0 + wrow)*K + wseg*8;

  for (int c0 = 0; c0 < K; c0 += 32) {
    uint4 va0 = *(const uint4*)(Ap + c0);
    uint4 va1 = *(const uint4*)(Ap + c0 + 8);
    uint4 vw  = *(const uint4*)(Wp + c0);
    *(uint4*)&As[arow][ahalf*16]     = va0;
    *(uint4*)&As[arow][ahalf*16 + 8] = va1;
    *(uint4*)&Bs[wrow][wseg*8]       = vw;
    __syncthreads();
    short8 bf[4];
#pragma unroll
    for (int mt = 0; mt < 4; mt++)
      bf[mt] = *(const short8*)&Bs[mt*16 + l15][quad*8];
#pragma unroll
    for (int nt = 0; nt < 2; nt++) {
      short8 af = *(const short8*)&As[wv*32 + nt*16 + l15][quad*8];
#pragma unroll
      for (int mt = 0; mt < 4; mt++)
        acc[nt][mt] = __builtin_amdgcn_mfma_f32_16x16x32_bf16(af, bf[mt], acc[nt][mt], 0, 0, 0);
    }
    __syncthreads();
  }

  if (EPI == 0 || EPI == 1) {
    float bs[4];
#pragma unroll
    for (int mt = 0; mt < 4; mt++)
      bs[mt] = (EPI == 1) ? p.bias[m0 + mt*16 + l15] : 0.f;
#pragma unroll
    for (int nt = 0; nt < 2; nt++)
#pragma unroll
      for (int reg = 0; reg < 4; reg++) {
        size_t row = ((size_t)(bb*NPT + n0 + wv*32 + nt*16 + quad*4 + reg))*p.M + m0;
#pragma unroll
        for (int mt = 0; mt < 4; mt++) {
          float v = acc[nt][mt][reg] + bs[mt];
          if (EPI == 1) v = fmaxf(v, 0.f);
          p.OutB[row + mt*16 + l15] = f2b(v);
        }
      }
  } else if (EPI == 2) {
    float sc[4], sh[4];
#pragma unroll
    for (int mt = 0; mt < 4; mt++) {
      int m = m0 + mt*16 + l15;
      float s = p.bng[m] / sqrtf(p.bnv[m] + EPSBN);
      sc[mt] = s; sh[mt] = p.bnb[m] - p.bnm[m]*s;
    }
#pragma unroll
    for (int nt = 0; nt < 2; nt++)
#pragma unroll
      for (int reg = 0; reg < 4; reg++) {
        size_t row = ((size_t)(bb*NPT + n0 + wv*32 + nt*16 + quad*4 + reg))*p.M + m0;
#pragma unroll
        for (int mt = 0; mt < 4; mt++) {
          float r = p.resid[row + mt*16 + l15];
          float v = (acc[nt][mt][reg] + r)*sc[mt] + sh[mt];
          p.OutF[row + mt*16 + l15] = v;
          p.OutB[row + mt*16 + l15] = f2b(v);
        }
      }
  } else {  // EPI == 3
    __shared__ float Tb[4][4][16*17];
    float sc[4], sh[4], bs[4];
#pragma unroll
    for (int mt = 0; mt < 4; mt++) {
      int m = m0 + mt*16 + l15;
      float s = p.bng[m] / sqrtf(p.bnv[m] + EPSBN);
      sc[mt] = s; sh[mt] = p.bnb[m] - p.bnm[m]*s;
      bs[mt] = p.bias[m];
    }
#pragma unroll
    for (int nt = 0; nt < 2; nt++) {
#pragma unroll
      for (int reg = 0; reg < 4; reg++) {
        size_t row = ((size_t)(bb*NPT + n0 + wv*32 + nt*16 + quad*4 + reg))*p.M + m0;
#pragma unroll
        for (int mt = 0; mt < 4; mt++) {
          float r = p.resid[row + mt*16 + l15];
          float v = (acc[nt][mt][reg] + bs[mt] + r)*sc[mt] + sh[mt];
          Tb[wv][mt][(quad*4 + reg)*17 + l15] = v;
        }
      }
      __syncthreads();
#pragma unroll
      for (int mt = 0; mt < 4; mt++)
#pragma unroll
        for (int reg = 0; reg < 4; reg++) {
          float v = Tb[wv][mt][l15*17 + quad*4 + reg];
          p.OutF[((size_t)(bb*p.M + m0 + mt*16 + quad*4 + reg))*NPT
                 + n0 + wv*32 + nt*16 + l15] = v;
        }
      __syncthreads();
    }
  }
}

extern "C" void kernel_launch(void* const* d_in, const int* in_sizes, int n_in,
                              void* d_out, int out_size, void* d_ws, size_t ws_size,
                              hipStream_t stream) {
  const float* x     = (const float*)d_in[0];
  const float* xyz   = (const float*)d_in[1];
  const float* Wq    = (const float*)d_in[2];
  const float* Wkv   = (const float*)d_in[3];
  const float* Wproj = (const float*)d_in[4];
  const float* rp_w1 = (const float*)d_in[5];
  const float* rp_g  = (const float*)d_in[6];
  const float* rp_b  = (const float*)d_in[7];
  const float* rp_m  = (const float*)d_in[8];
  const float* rp_v  = (const float*)d_in[9];
  const float* rp_w2 = (const float*)d_in[10];
  const float* bn1_g = (const float*)d_in[11];
  const float* bn1_b = (const float*)d_in[12];
  const float* bn1_m = (const float*)d_in[13];
  const float* bn1_v = (const float*)d_in[14];
  const float* bn2_g = (const float*)d_in[15];
  const float* bn2_b = (const float*)d_in[16];
  const float* bn2_m = (const float*)d_in[17];
  const float* bn2_v = (const float*)d_in[18];
  const float* ffn_w1 = (const float*)d_in[19];
  const float* ffn_b1 = (const float*)d_in[20];
  const float* ffn_w2 = (const float*)d_in[21];
  const float* ffn_b2 = (const float*)d_in[22];

  char* ws = (char*)d_ws;
  // static region
  float4* w1f = (float4*)(ws + 0);                         //   4 KB
  float4* W2t = (float4*)(ws + 4096);                      //   4 KB
  int*    idx = (int*)  (ws + 8192);                       // 512 KB
  // reuse region A (32 MB): KNN scratch first, then post-attn tensors
  const size_t oA = 532480;
  float4*         Pp     = (float4*)(ws + oA);             // 32 MB [B*N][512] (d,idx)
  unsigned short* attn_b = (unsigned short*)(ws + oA);                 //  4 MB bf16 [B][N][256]
  float*          x1f    = (float*)(ws + oA + (4u<<20));               //  8 MB fp32 [B][N][256]
  unsigned short* x1b    = (unsigned short*)(ws + oA + (12u<<20));     //  4 MB bf16 [B][N][256]
  unsigned short* h_b    = (unsigned short*)(ws + oA + (16u<<20));     // 16 MB bf16 [B][N][1024]
  // region B: weights + casted x + qkv + bias
  const size_t oB = oA + (32u<<20);
  unsigned short* Wqkv_b  = (unsigned short*)(ws + oB);                // 384 KB [768][256]
  unsigned short* Wproj_b = (unsigned short*)(ws + oB + 393216);       // 128 KB
  unsigned short* W1_b    = (unsigned short*)(ws + oB + 524288);       // 512 KB
  unsigned short* W2_b    = (unsigned short*)(ws + oB + 1048576);      // 512 KB
  unsigned short* xb      = (unsigned short*)(ws + oB + 1572864);      //   4 MB bf16 [B][N][256]
  float*          xf      = (float*)(ws + oB + 1572864 + (4u<<20));    //   8 MB fp32 [B][N][256]
  unsigned short* qkv     = (unsigned short*)(ws + oB + 1572864 + (12u<<20)); // 12 MB bf16 [B][N][768]
  float*          biasB   = (float*)(ws + oB + 1572864 + (24u<<20));   //   2 MB [B][N][16][4]

  prep_kernel<<<1, 256, 0, stream>>>(rp_w1, rp_g, rp_b, rp_m, rp_v, rp_w2, w1f, W2t);
  wcast_kernel<<<3072, 256, 0, stream>>>(Wq, Wkv, Wproj, ffn_w1, ffn_w2,
                                         Wqkv_b, Wproj_b, W1_b, W2_b);
  xcast_kernel<<<dim3(64, 4, BB), 256, 0, stream>>>(x, xb, xf);

  knn_partial_kernel<<<dim3(8, 64, BB), 256, 0, stream>>>(xyz, Pp);
  knn_merge_kernel<<<(BB*NPT)/4, 256, 0, stream>>>(Pp, idx);

  MG pqkv = {xb, Wqkv_b, 256, 768, qkv, nullptr,
             nullptr, nullptr, nullptr, nullptr, nullptr, nullptr};
  mgemm_kernel<0><<<dim3(32, 12, BB), 256, 0, stream>>>(pqkv);

  bias_kernel<<<(BB*NPT*KNN)/256, 256, 0, stream>>>(xyz, idx, w1f, W2t, (float4*)biasB);
  attn_kernel<<<BB*NPT, 256, 0, stream>>>(qkv, biasB, idx, attn_b);

  MG pproj = {attn_b, Wproj_b, 256, 256, x1b, x1f,
              nullptr, xf, bn1_g, bn1_b, bn1_m, bn1_v};
  mgemm_kernel<2><<<dim3(32, 4, BB), 256, 0, stream>>>(pproj);

  MG pf1 = {x1b, W1_b, 256, 1024, h_b, nullptr,
            ffn_b1, nullptr, nullptr, nullptr, nullptr, nullptr};
  mgemm_kernel<1><<<dim3(32, 16, BB), 256, 0, stream>>>(pf1);

  MG pf2 = {h_b, W2_b, 1024, 256, nullptr, (float*)d_out,
            ffn_b2, x1f, bn2_g, bn2_b, bn2_m, bn2_v};
  mgemm_kernel<3><<<dim3(32, 4, BB), 256, 0, stream>>>(pf2);
}

// Round 8
// 308.412 us; speedup vs baseline: 4.5379x; 1.0128x over previous
//
#include <hip/hip_runtime.h>
#include <math.h>

#define BB   2
#define CC   256
#define NPT  4096
#define HH   4
#define DD   64
#define KNN  16
#define EPSBN 1e-5f

typedef __attribute__((ext_vector_type(8))) short short8;
typedef __attribute__((ext_vector_type(4))) float f32x4;

__device__ __forceinline__ unsigned short f2b(float f) {
  union { float f; unsigned int u; } v; v.f = f;
  unsigned int r = (v.u + 0x7FFFu + ((v.u >> 16) & 1u)) >> 16;
  return (unsigned short)r;
}
__device__ __forceinline__ float b2f(unsigned short h) {
  union { unsigned int u; float f; } v; v.u = ((unsigned int)h) << 16;
  return v.f;
}
__device__ __forceinline__ void up2(unsigned int u, float& a, float& b) {
  union { unsigned int x; float f; } lo, hi;
  lo.x = u << 16; hi.x = u & 0xffff0000u;
  a = lo.f; b = hi.f;
}
__device__ __forceinline__ void up16(uint4 u0, uint4 u1, float* f) {
  up2(u0.x, f[0], f[1]);  up2(u0.y, f[2], f[3]);
  up2(u0.z, f[4], f[5]);  up2(u0.w, f[6], f[7]);
  up2(u1.x, f[8], f[9]);  up2(u1.y, f[10], f[11]);
  up2(u1.z, f[12], f[13]); up2(u1.w, f[14], f[15]);
}

// ---------------- prep: fold rp BN into w1, reduce rp_w2 over heads ----------------
__global__ __launch_bounds__(256)
void prep_kernel(const float* __restrict__ rp_w1, const float* __restrict__ rp_g,
                 const float* __restrict__ rp_b,  const float* __restrict__ rp_m,
                 const float* __restrict__ rp_v,  const float* __restrict__ rp_w2,
                 float4* __restrict__ w1f, float4* __restrict__ W2t) {
  int c = threadIdx.x;
  float s  = rp_g[c] / sqrtf(rp_v[c] + EPSBN);
  float b0 = rp_b[c] - rp_m[c] * s;
  w1f[c] = make_float4(rp_w1[c*3+0]*s, rp_w1[c*3+1]*s, rp_w1[c*3+2]*s, b0);
  float a0=0.f,a1=0.f,a2=0.f,a3=0.f;
  for (int o = 0; o < 64; o++) {
    a0 += rp_w2[(      o)*CC + c];
    a1 += rp_w2[( 64 + o)*CC + c];
    a2 += rp_w2[(128 + o)*CC + c];
    a3 += rp_w2[(192 + o)*CC + c];
  }
  W2t[c] = make_float4(a0,a1,a2,a3);
}

// ---------------- cast weights to bf16 (qkv rows concatenated [Wq;Wkv]) ------------
__global__ __launch_bounds__(256)
void wcast_kernel(const float* __restrict__ Wq, const float* __restrict__ Wkv,
                  const float* __restrict__ Wp, const float* __restrict__ W1,
                  const float* __restrict__ W2,
                  unsigned short* __restrict__ oQKV, unsigned short* __restrict__ oP,
                  unsigned short* __restrict__ o1,   unsigned short* __restrict__ o2) {
  int i = blockIdx.x * 256 + threadIdx.x;          // 786432 total
  if (i < 65536)        oQKV[i] = f2b(Wq[i]);
  else if (i < 196608)  oQKV[i] = f2b(Wkv[i - 65536]);
  else if (i < 262144)  oP[i - 196608] = f2b(Wp[i - 196608]);
  else if (i < 524288)  o1[i - 262144] = f2b(W1[i - 262144]);
  else                  o2[i - 524288] = f2b(W2[i - 524288]);
}

// ---------------- transpose+cast x: [B][C][N] fp32 -> [B][N][C] bf16 + fp32 --------
__global__ __launch_bounds__(256)
void xcast_kernel(const float* __restrict__ x, unsigned short* __restrict__ xb,
                  float* __restrict__ xf) {
  __shared__ float T[64][65];
  int n0 = blockIdx.x * 64, c0 = blockIdx.y * 64, bb = blockIdx.z;
  int tid = threadIdx.x;
  {
    int crow = tid >> 2, ns = (tid & 3) * 16;
    const float* xp = x + ((size_t)(bb*CC + c0 + crow))*NPT + n0 + ns;
#pragma unroll
    for (int i = 0; i < 4; i++) {
      float4 v = ((const float4*)xp)[i];
      T[crow][ns + i*4 + 0] = v.x; T[crow][ns + i*4 + 1] = v.y;
      T[crow][ns + i*4 + 2] = v.z; T[crow][ns + i*4 + 3] = v.w;
    }
  }
  __syncthreads();
  {
    int nrow = tid >> 2, cs = (tid & 3) * 16;
    float vals[16];
#pragma unroll
    for (int i = 0; i < 16; i++) vals[i] = T[cs + i][nrow];
    size_t orow = ((size_t)(bb*NPT + n0 + nrow))*CC + c0 + cs;
#pragma unroll
    for (int i = 0; i < 4; i++)
      *(float4*)&xf[orow + i*4] = make_float4(vals[i*4], vals[i*4+1], vals[i*4+2], vals[i*4+3]);
    unsigned short us[16];
#pragma unroll
    for (int i = 0; i < 16; i++) us[i] = f2b(vals[i]);
    *(uint4*)&xb[orow]     = *(const uint4*)&us[0];
    *(uint4*)&xb[orow + 8] = *(const uint4*)&us[8];
  }
}

// ---------------- KNN stage 1: branch-free sorted insert, f32 dist + i32 idx -------
// amdgpu_waves_per_eu(1,4): CAP occupancy at 4 waves/EU so the register budget is
// 128/wave and the 16 (dist,idx) pairs stay in arch VGPRs. launch_bounds(256,4)
// only sets the MIN waves/EU and left the allocator targeting 64 regs -> AGPR
// shuttling at ~165 instr/eval (R6/R7 post-mortem). Grid = 4 blocks/CU anyway,
// so >4 waves/EU is unreachable and the cap costs nothing.
#define KSTEP(KD,KI) { bool c = nd < KD; float dl = c ? nd : KD; int il = c ? ni : KI; \
                       nd = c ? KD : nd; ni = c ? KI : ni; KD = dl; KI = il; }
__global__ __launch_bounds__(256) __attribute__((amdgpu_waves_per_eu(1, 4)))
void knn_partial_kernel(const float* __restrict__ xyz, float4* __restrict__ Pp) {
  __shared__ float4 sp[512];    // (x, y, z, |p|^2)
  int s  = blockIdx.x;          // candidate slice 0..7
  int qg = blockIdx.y;          // query group 0..63
  int b  = blockIdx.z;
  const float* base = xyz + (size_t)b * 3 * NPT;
  int c0 = s * 512;
  for (int i = threadIdx.x; i < 512; i += 256) {
    float mx = base[c0 + i], my = base[NPT + c0 + i], mz = base[2*NPT + c0 + i];
    sp[i] = make_float4(mx, my, mz, mx*mx + my*my + mz*mz);
  }
  int lane = threadIdx.x & 63;
  int wv   = threadIdx.x >> 6;
  int qn   = qg * 64 + lane;
  float qx = base[qn], qy = base[NPT + qn], qz = base[2*NPT + qn];
  float qsq = qx*qx + qy*qy + qz*qz;
  float qx2 = -2.f*qx, qy2 = -2.f*qy, qz2 = -2.f*qz;
  __syncthreads();

  const float INF = 3.4e38f;
  float kd0=INF,kd1=INF,kd2=INF,kd3=INF,kd4=INF,kd5=INF,kd6=INF,kd7=INF,
        kd8=INF,kd9=INF,kd10=INF,kd11=INF,kd12=INF,kd13=INF,kd14=INF,kd15=INF;
  int   ki0=0x7fffffff,ki1=0x7fffffff,ki2=0x7fffffff,ki3=0x7fffffff,
        ki4=0x7fffffff,ki5=0x7fffffff,ki6=0x7fffffff,ki7=0x7fffffff,
        ki8=0x7fffffff,ki9=0x7fffffff,ki10=0x7fffffff,ki11=0x7fffffff,
        ki12=0x7fffffff,ki13=0x7fffffff,ki14=0x7fffffff,ki15=0x7fffffff;

  int mbase = wv * 128;
#pragma unroll 2
  for (int mm = 0; mm < 128; mm++) {
    int m = mbase + mm;
    float4 m4 = sp[m];                       // wave-uniform broadcast read
    float nd = fmaf(qx2, m4.x, fmaf(qy2, m4.y, fmaf(qz2, m4.z, m4.w + qsq)));
    int   ni = c0 + m;
    KSTEP(kd0,ki0)   KSTEP(kd1,ki1)   KSTEP(kd2,ki2)   KSTEP(kd3,ki3)
    KSTEP(kd4,ki4)   KSTEP(kd5,ki5)   KSTEP(kd6,ki6)   KSTEP(kd7,ki7)
    KSTEP(kd8,ki8)   KSTEP(kd9,ki9)   KSTEP(kd10,ki10) KSTEP(kd11,ki11)
    KSTEP(kd12,ki12) KSTEP(kd13,ki13) KSTEP(kd14,ki14) KSTEP(kd15,ki15)
  }

  int gq = b * NPT + qn;
  float4* out = Pp + (size_t)gq * 256 + (s*4 + wv)*8;   // 128B contiguous per thread
  out[0] = make_float4(kd0,  __int_as_float(ki0),  kd1,  __int_as_float(ki1));
  out[1] = make_float4(kd2,  __int_as_float(ki2),  kd3,  __int_as_float(ki3));
  out[2] = make_float4(kd4,  __int_as_float(ki4),  kd5,  __int_as_float(ki5));
  out[3] = make_float4(kd6,  __int_as_float(ki6),  kd7,  __int_as_float(ki7));
  out[4] = make_float4(kd8,  __int_as_float(ki8),  kd9,  __int_as_float(ki9));
  out[5] = make_float4(kd10, __int_as_float(ki10), kd11, __int_as_float(ki11));
  out[6] = make_float4(kd12, __int_as_float(ki12), kd13, __int_as_float(ki13));
  out[7] = make_float4(kd14, __int_as_float(ki14), kd15, __int_as_float(ki15));
}

// ---------------- KNN stage 2: one WAVE per query, 8 entries/lane, 16 select-min rounds ----
__global__ __launch_bounds__(256)
void knn_merge_kernel(const float4* __restrict__ Pp, int* __restrict__ idx_out) {
  int wv   = threadIdx.x >> 6;
  int lane = threadIdx.x & 63;
  int gq   = blockIdx.x * 4 + wv;
  float d[8]; int ii[8];
  const float4* base = Pp + (size_t)gq * 256;
#pragma unroll
  for (int j = 0; j < 4; j++) {
    float4 v = base[j*64 + lane];
    d[2*j+0] = v.x; ii[2*j+0] = __float_as_int(v.y);
    d[2*j+1] = v.z; ii[2*j+1] = __float_as_int(v.w);
  }
  for (int sel = 0; sel < 16; sel++) {
    float bd = 3.5e38f; int bi = 0x7fffffff;
#pragma unroll
    for (int t = 0; t < 8; t++) {
      bool better = (d[t] < bd) || (d[t] == bd && ii[t] < bi);
      if (better) { bd = d[t]; bi = ii[t]; }
    }
#pragma unroll
    for (int off = 1; off < 64; off <<= 1) {
      float od = __shfl_xor(bd, off, 64);
      int   oi = __shfl_xor(bi, off, 64);
      if (od < bd || (od == bd && oi < bi)) { bd = od; bi = oi; }
    }
#pragma unroll
    for (int t = 0; t < 8; t++)
      if (ii[t] == bi) d[t] = 3.5e38f;
    if (lane == 0) idx_out[gq*16 + sel] = bi;
  }
}

// ---------------- fused rel-pos bias (unchanged) ----------------
__global__ __launch_bounds__(256)
void bias_kernel(const float* __restrict__ xyz, const int* __restrict__ idx,
                 const float4* __restrict__ w1f, const float4* __restrict__ W2t,
                 float4* __restrict__ biasB) {
  __shared__ float4 sw1[256];
  __shared__ float4 sw2[256];
  int tid = threadIdx.x;
  sw1[tid] = w1f[tid];
  sw2[tid] = W2t[tid];
  __syncthreads();
  int gid = blockIdx.x * 256 + tid;
  int b = gid >> 16;
  int n = (gid >> 4) & 4095;
  int j = idx[gid];
  const float* base = xyz + (size_t)b * 3 * NPT;
  float rx = base[j]         - base[n];
  float ry = base[NPT + j]   - base[NPT + n];
  float rz = base[2*NPT + j] - base[2*NPT + n];
  float a0=0.f,a1=0.f,a2=0.f,a3=0.f;
#pragma unroll 8
  for (int c = 0; c < 256; c++) {
    float4 w = sw1[c];
    float t = fmaf(rx, w.x, fmaf(ry, w.y, fmaf(rz, w.z, w.w)));
    t = fmaxf(t, 0.f);
    float4 w2 = sw2[c];
    a0 = fmaf(t, w2.x, a0); a1 = fmaf(t, w2.y, a1);
    a2 = fmaf(t, w2.z, a2); a3 = fmaf(t, w2.w, a3);
  }
  biasB[gid] = make_float4(a0,a1,a2,a3);
}

// ---------------- fused attention v2: lane = (neighbor k, 16-ch chunk) -------------
__global__ __launch_bounds__(256, 4)
void attn_kernel(const unsigned short* __restrict__ qkv, const float* __restrict__ biasB,
                 const int* __restrict__ idx, unsigned short* __restrict__ attn_b) {
  __shared__ int sidx[16];
  __shared__ float red[4][16*68];   // per-wave [k][68] rows, 17408 B total
  int bn = blockIdx.x;
  int b  = bn >> 12;
  if (threadIdx.x < 16) sidx[threadIdx.x] = idx[bn*16 + threadIdx.x];
  __syncthreads();
  int wv   = threadIdx.x >> 6;      // head
  int lane = threadIdx.x & 63;
  int k    = lane >> 2;             // neighbor
  int c4   = lane & 3;              // channel chunk
  int ch0  = wv*64 + c4*16;
  size_t rowq = (size_t)bn * 768;
  size_t base = (size_t)(b*NPT) * 768;

  float qf[16];
  {
    uint4 q0 = *(const uint4*)(qkv + rowq + ch0);
    uint4 q1 = *(const uint4*)(qkv + rowq + ch0 + 8);
    up16(q0, q1, qf);
  }
  int j = sidx[k];
  float dot = 0.f;
  {
    const unsigned short* krow = qkv + base + (size_t)j*768 + 256 + ch0;
    uint4 k0 = *(const uint4*)(krow);
    uint4 k1 = *(const uint4*)(krow + 8);
    float kf[16];
    up16(k0, k1, kf);
#pragma unroll
    for (int i = 0; i < 16; i++) dot = fmaf(qf[i], kf[i], dot);
  }
  dot += __shfl_xor(dot, 1, 64);
  dot += __shfl_xor(dot, 2, 64);
  float logit = dot * 0.125f + biasB[(size_t)(bn*16 + k)*4 + wv];
  float mx = logit;
#pragma unroll
  for (int off = 4; off < 64; off <<= 1) mx = fmaxf(mx, __shfl_xor(mx, off, 64));
  float e = __expf(logit - mx);
  float ssum = e;
#pragma unroll
  for (int off = 4; off < 64; off <<= 1) ssum += __shfl_xor(ssum, off, 64);
  float w = e / ssum;

  {
    const unsigned short* vrow = qkv + base + (size_t)j*768 + 512 + ch0;
    uint4 v0 = *(const uint4*)(vrow);
    uint4 v1 = *(const uint4*)(vrow + 8);
    float vf[16];
    up16(v0, v1, vf);
    float* dst = &red[wv][k*68 + c4*16];
#pragma unroll
    for (int g = 0; g < 4; g++)
      ((float4*)dst)[g] = make_float4(w*vf[g*4], w*vf[g*4+1], w*vf[g*4+2], w*vf[g*4+3]);
  }
  __syncthreads();
  float o = 0.f;
#pragma unroll
  for (int kk = 0; kk < 16; kk++) o += red[wv][kk*68 + lane];   // 2-way = free
  attn_b[(size_t)bn*256 + wv*64 + lane] = f2b(o);
}

// ---------------- MFMA bf16 GEMM: D[n][m] = A[n][k] * W[m][k] ----------------
struct MG {
  const unsigned short* A; const unsigned short* Wt; int K; int M;
  unsigned short* OutB; float* OutF;
  const float* bias; const float* resid;
  const float* bng; const float* bnb; const float* bnm; const float* bnv;
};

template<int EPI>
__global__ __launch_bounds__(256)
void mgemm_kernel(MG p) {
  __shared__ unsigned short As[128][40];
  __shared__ unsigned short Bs[64][40];
  const int tid  = threadIdx.x;
  const int bb   = blockIdx.z;
  const int n0   = blockIdx.x * 128;
  const int m0   = blockIdx.y * 64;
  const int lane = tid & 63;
  const int wv   = tid >> 6;
  const int l15  = lane & 15;
  const int quad = lane >> 4;
  const int K    = p.K;

  f32x4 acc[2][4];
#pragma unroll
  for (int i = 0; i < 2; i++)
#pragma unroll
    for (int j = 0; j < 4; j++) acc[i][j] = (f32x4){0.f, 0.f, 0.f, 0.f};

  const int arow = tid >> 1, ahalf = tid & 1;
  const int wrow = tid >> 2, wseg = tid & 3;
  const unsigned short* Ap = p.A  + (size_t)(bb*NPT + n0 + arow)*K + ahalf*16;
  const unsigned short* Wp = p.Wt + (size_t)(m0 + wrow)*K + wseg*8;

  for (int c0 = 0; c0 < K; c0 += 32) {
    uint4 va0 = *(const uint4*)(Ap + c0);
    uint4 va1 = *(const uint4*)(Ap + c0 + 8);
    uint4 vw  = *(const uint4*)(Wp + c0);
    *(uint4*)&As[arow][ahalf*16]     = va0;
    *(uint4*)&As[arow][ahalf*16 + 8] = va1;
    *(uint4*)&Bs[wrow][wseg*8]       = vw;
    __syncthreads();
    short8 bf[4];
#pragma unroll
    for (int mt = 0; mt < 4; mt++)
      bf[mt] = *(const short8*)&Bs[mt*16 + l15][quad*8];
#pragma unroll
    for (int nt = 0; nt < 2; nt++) {
      short8 af = *(const short8*)&As[wv*32 + nt*16 + l15][quad*8];
#pragma unroll
      for (int mt = 0; mt < 4; mt++)
        acc[nt][mt] = __builtin_amdgcn_mfma_f32_16x16x32_bf16(af, bf[mt], acc[nt][mt], 0, 0, 0);
    }
    __syncthreads();
  }

  if (EPI == 0 || EPI == 1) {
    float bs[4];
#pragma unroll
    for (int mt = 0; mt < 4; mt++)
      bs[mt] = (EPI == 1) ? p.bias[m0 + mt*16 + l15] : 0.f;
#pragma unroll
    for (int nt = 0; nt < 2; nt++)
#pragma unroll
      for (int reg = 0; reg < 4; reg++) {
        size_t row = ((size_t)(bb*NPT + n0 + wv*32 + nt*16 + quad*4 + reg))*p.M + m0;
#pragma unroll
        for (int mt = 0; mt < 4; mt++) {
          float v = acc[nt][mt][reg] + bs[mt];
          if (EPI == 1) v = fmaxf(v, 0.f);
          p.OutB[row + mt*16 + l15] = f2b(v);
        }
      }
  } else if (EPI == 2) {
    float sc[4], sh[4];
#pragma unroll
    for (int mt = 0; mt < 4; mt++) {
      int m = m0 + mt*16 + l15;
      float s = p.bng[m] / sqrtf(p.bnv[m] + EPSBN);
      sc[mt] = s; sh[mt] = p.bnb[m] - p.bnm[m]*s;
    }
#pragma unroll
    for (int nt = 0; nt < 2; nt++)
#pragma unroll
      for (int reg = 0; reg < 4; reg++) {
        size_t row = ((size_t)(bb*NPT + n0 + wv*32 + nt*16 + quad*4 + reg))*p.M + m0;
#pragma unroll
        for (int mt = 0; mt < 4; mt++) {
          float r = p.resid[row + mt*16 + l15];
          float v = (acc[nt][mt][reg] + r)*sc[mt] + sh[mt];
          p.OutF[row + mt*16 + l15] = v;
          p.OutB[row + mt*16 + l15] = f2b(v);
        }
      }
  } else {  // EPI == 3
    __shared__ float Tb[4][4][16*17];
    float sc[4], sh[4], bs[4];
#pragma unroll
    for (int mt = 0; mt < 4; mt++) {
      int m = m0 + mt*16 + l15;
      float s = p.bng[m] / sqrtf(p.bnv[m] + EPSBN);
      sc[mt] = s; sh[mt] = p.bnb[m] - p.bnm[m]*s;
      bs[mt] = p.bias[m];
    }
#pragma unroll
    for (int nt = 0; nt < 2; nt++) {
#pragma unroll
      for (int reg = 0; reg < 4; reg++) {
        size_t row = ((size_t)(bb*NPT + n0 + wv*32 + nt*16 + quad*4 + reg))*p.M + m0;
#pragma unroll
        for (int mt = 0; mt < 4; mt++) {
          float r = p.resid[row + mt*16 + l15];
          float v = (acc[nt][mt][reg] + bs[mt] + r)*sc[mt] + sh[mt];
          Tb[wv][mt][(quad*4 + reg)*17 + l15] = v;
        }
      }
      __syncthreads();
#pragma unroll
      for (int mt = 0; mt < 4; mt++)
#pragma unroll
        for (int reg = 0; reg < 4; reg++) {
          float v = Tb[wv][mt][l15*17 + quad*4 + reg];
          p.OutF[((size_t)(bb*p.M + m0 + mt*16 + quad*4 + reg))*NPT
                 + n0 + wv*32 + nt*16 + l15] = v;
        }
      __syncthreads();
    }
  }
}

extern "C" void kernel_launch(void* const* d_in, const int* in_sizes, int n_in,
                              void* d_out, int out_size, void* d_ws, size_t ws_size,
                              hipStream_t stream) {
  const float* x     = (const float*)d_in[0];
  const float* xyz   = (const float*)d_in[1];
  const float* Wq    = (const float*)d_in[2];
  const float* Wkv   = (const float*)d_in[3];
  const float* Wproj = (const float*)d_in[4];
  const float* rp_w1 = (const float*)d_in[5];
  const float* rp_g  = (const float*)d_in[6];
  const float* rp_b  = (const float*)d_in[7];
  const float* rp_m  = (const float*)d_in[8];
  const float* rp_v  = (const float*)d_in[9];
  const float* rp_w2 = (const float*)d_in[10];
  const float* bn1_g = (const float*)d_in[11];
  const float* bn1_b = (const float*)d_in[12];
  const float* bn1_m = (const float*)d_in[13];
  const float* bn1_v = (const float*)d_in[14];
  const float* bn2_g = (const float*)d_in[15];
  const float* bn2_b = (const float*)d_in[16];
  const float* bn2_m = (const float*)d_in[17];
  const float* bn2_v = (const float*)d_in[18];
  const float* ffn_w1 = (const float*)d_in[19];
  const float* ffn_b1 = (const float*)d_in[20];
  const float* ffn_w2 = (const float*)d_in[21];
  const float* ffn_b2 = (const float*)d_in[22];

  char* ws = (char*)d_ws;
  // static region
  float4* w1f = (float4*)(ws + 0);                         //   4 KB
  float4* W2t = (float4*)(ws + 4096);                      //   4 KB
  int*    idx = (int*)  (ws + 8192);                       // 512 KB
  // reuse region A (32 MB): KNN scratch first, then post-attn tensors
  const size_t oA = 532480;
  float4*         Pp     = (float4*)(ws + oA);             // 32 MB [B*N][512] (d,idx)
  unsigned short* attn_b = (unsigned short*)(ws + oA);                 //  4 MB bf16 [B][N][256]
  float*          x1f    = (float*)(ws + oA + (4u<<20));               //  8 MB fp32 [B][N][256]
  unsigned short* x1b    = (unsigned short*)(ws + oA + (12u<<20));     //  4 MB bf16 [B][N][256]
  unsigned short* h_b    = (unsigned short*)(ws + oA + (16u<<20));     // 16 MB bf16 [B][N][1024]
  // region B: weights + casted x + qkv + bias
  const size_t oB = oA + (32u<<20);
  unsigned short* Wqkv_b  = (unsigned short*)(ws + oB);                // 384 KB [768][256]
  unsigned short* Wproj_b = (unsigned short*)(ws + oB + 393216);       // 128 KB
  unsigned short* W1_b    = (unsigned short*)(ws + oB + 524288);       // 512 KB
  unsigned short* W2_b    = (unsigned short*)(ws + oB + 1048576);      // 512 KB
  unsigned short* xb      = (unsigned short*)(ws + oB + 1572864);      //   4 MB bf16 [B][N][256]
  float*          xf      = (float*)(ws + oB + 1572864 + (4u<<20));    //   8 MB fp32 [B][N][256]
  unsigned short* qkv     = (unsigned short*)(ws + oB + 1572864 + (12u<<20)); // 12 MB bf16 [B][N][768]
  float*          biasB   = (float*)(ws + oB + 1572864 + (24u<<20));   //   2 MB [B][N][16][4]

  prep_kernel<<<1, 256, 0, stream>>>(rp_w1, rp_g, rp_b, rp_m, rp_v, rp_w2, w1f, W2t);
  wcast_kernel<<<3072, 256, 0, stream>>>(Wq, Wkv, Wproj, ffn_w1, ffn_w2,
                                         Wqkv_b, Wproj_b, W1_b, W2_b);
  xcast_kernel<<<dim3(64, 4, BB), 256, 0, stream>>>(x, xb, xf);

  knn_partial_kernel<<<dim3(8, 64, BB), 256, 0, stream>>>(xyz, Pp);
  knn_merge_kernel<<<(BB*NPT)/4, 256, 0, stream>>>(Pp, idx);

  MG pqkv = {xb, Wqkv_b, 256, 768, qkv, nullptr,
             nullptr, nullptr, nullptr, nullptr, nullptr, nullptr};
  mgemm_kernel<0><<<dim3(32, 12, BB), 256, 0, stream>>>(pqkv);

  bias_kernel<<<(BB*NPT*KNN)/256, 256, 0, stream>>>(xyz, idx, w1f, W2t, (float4*)biasB);
  attn_kernel<<<BB*NPT, 256, 0, stream>>>(qkv, biasB, idx, attn_b);

  MG pproj = {attn_b, Wproj_b, 256, 256, x1b, x1f,
              nullptr, xf, bn1_g, bn1_b, bn1_m, bn1_v};
  mgemm_kernel<2><<<dim3(32, 4, BB), 256, 0, stream>>>(pproj);

  MG pf1 = {x1b, W1_b, 256, 1024, h_b, nullptr,
            ffn_b1, nullptr, nullptr, nullptr, nullptr, nullptr};
  mgemm_kernel<1><<<dim3(32, 16, BB), 256, 0, stream>>>(pf1);

  MG pf2 = {h_b, W2_b, 1024, 256, nullptr, (float*)d_out,
            ffn_b2, x1f, bn2_g, bn2_b, bn2_m, bn2_v};
  mgemm_kernel<3><<<dim3(32, 4, BB), 256, 0, stream>>>(pf2);
}

// Round 9
// 277.302 us; speedup vs baseline: 5.0470x; 1.1122x over previous
//
#include <hip/hip_runtime.h>
#include <math.h>

#define BB   2
#define CC   256
#define NPT  4096
#define HH   4
#define DD   64
#define KNN  16
#define EPSBN 1e-5f

typedef __attribute__((ext_vector_type(8))) short short8;
typedef __attribute__((ext_vector_type(4))) float f32x4;

__device__ __forceinline__ unsigned short f2b(float f) {
  union { float f; unsigned int u; } v; v.f = f;
  unsigned int r = (v.u + 0x7FFFu + ((v.u >> 16) & 1u)) >> 16;
  return (unsigned short)r;
}
__device__ __forceinline__ float b2f(unsigned short h) {
  union { unsigned int u; float f; } v; v.u = ((unsigned int)h) << 16;
  return v.f;
}
__device__ __forceinline__ void up2(unsigned int u, float& a, float& b) {
  union { unsigned int x; float f; } lo, hi;
  lo.x = u << 16; hi.x = u & 0xffff0000u;
  a = lo.f; b = hi.f;
}
__device__ __forceinline__ void up16(uint4 u0, uint4 u1, float* f) {
  up2(u0.x, f[0], f[1]);  up2(u0.y, f[2], f[3]);
  up2(u0.z, f[4], f[5]);  up2(u0.w, f[6], f[7]);
  up2(u1.x, f[8], f[9]);  up2(u1.y, f[10], f[11]);
  up2(u1.z, f[12], f[13]); up2(u1.w, f[14], f[15]);
}

// ---------------- prep: fold rp BN into w1, reduce rp_w2 over heads ----------------
__global__ __launch_bounds__(256)
void prep_kernel(const float* __restrict__ rp_w1, const float* __restrict__ rp_g,
                 const float* __restrict__ rp_b,  const float* __restrict__ rp_m,
                 const float* __restrict__ rp_v,  const float* __restrict__ rp_w2,
                 float4* __restrict__ w1f, float4* __restrict__ W2t) {
  int c = threadIdx.x;
  float s  = rp_g[c] / sqrtf(rp_v[c] + EPSBN);
  float b0 = rp_b[c] - rp_m[c] * s;
  w1f[c] = make_float4(rp_w1[c*3+0]*s, rp_w1[c*3+1]*s, rp_w1[c*3+2]*s, b0);
  float a0=0.f,a1=0.f,a2=0.f,a3=0.f;
  for (int o = 0; o < 64; o++) {
    a0 += rp_w2[(      o)*CC + c];
    a1 += rp_w2[( 64 + o)*CC + c];
    a2 += rp_w2[(128 + o)*CC + c];
    a3 += rp_w2[(192 + o)*CC + c];
  }
  W2t[c] = make_float4(a0,a1,a2,a3);
}

// ---------------- cast weights to bf16 (qkv rows concatenated [Wq;Wkv]) ------------
__global__ __launch_bounds__(256)
void wcast_kernel(const float* __restrict__ Wq, const float* __restrict__ Wkv,
                  const float* __restrict__ Wp, const float* __restrict__ W1,
                  const float* __restrict__ W2,
                  unsigned short* __restrict__ oQKV, unsigned short* __restrict__ oP,
                  unsigned short* __restrict__ o1,   unsigned short* __restrict__ o2) {
  int i = blockIdx.x * 256 + threadIdx.x;          // 786432 total
  if (i < 65536)        oQKV[i] = f2b(Wq[i]);
  else if (i < 196608)  oQKV[i] = f2b(Wkv[i - 65536]);
  else if (i < 262144)  oP[i - 196608] = f2b(Wp[i - 196608]);
  else if (i < 524288)  o1[i - 262144] = f2b(W1[i - 262144]);
  else                  o2[i - 524288] = f2b(W2[i - 524288]);
}

// ---------------- transpose+cast x: [B][C][N] fp32 -> [B][N][C] bf16 + fp32 --------
__global__ __launch_bounds__(256)
void xcast_kernel(const float* __restrict__ x, unsigned short* __restrict__ xb,
                  float* __restrict__ xf) {
  __shared__ float T[64][65];
  int n0 = blockIdx.x * 64, c0 = blockIdx.y * 64, bb = blockIdx.z;
  int tid = threadIdx.x;
  {
    int crow = tid >> 2, ns = (tid & 3) * 16;
    const float* xp = x + ((size_t)(bb*CC + c0 + crow))*NPT + n0 + ns;
#pragma unroll
    for (int i = 0; i < 4; i++) {
      float4 v = ((const float4*)xp)[i];
      T[crow][ns + i*4 + 0] = v.x; T[crow][ns + i*4 + 1] = v.y;
      T[crow][ns + i*4 + 2] = v.z; T[crow][ns + i*4 + 3] = v.w;
    }
  }
  __syncthreads();
  {
    int nrow = tid >> 2, cs = (tid & 3) * 16;
    float vals[16];
#pragma unroll
    for (int i = 0; i < 16; i++) vals[i] = T[cs + i][nrow];
    size_t orow = ((size_t)(bb*NPT + n0 + nrow))*CC + c0 + cs;
#pragma unroll
    for (int i = 0; i < 4; i++)
      *(float4*)&xf[orow + i*4] = make_float4(vals[i*4], vals[i*4+1], vals[i*4+2], vals[i*4+3]);
    unsigned short us[16];
#pragma unroll
    for (int i = 0; i < 16; i++) us[i] = f2b(vals[i]);
    *(uint4*)&xb[orow]     = *(const uint4*)&us[0];
    *(uint4*)&xb[orow + 8] = *(const uint4*)&us[8];
  }
}

// ---------------- KNN stage 1: packed-u32 min/max compare-swap network -------------
// key = (dist_bits & 0xFFFFFE00) | m  (dist clamped >=0 -> bits order-monotonic;
// m = 9-bit slice-local index). Sorted-insert step = v_min_u32 + v_max_u32 ONLY:
// 2 VALU/step vs ~10 for the cmp+cndmask pattern (R6-R8 post-mortems: the select
// formulation costs 168 instr/eval however phrased). Tie semantics: lex on
// (14-bit-truncated dist, idx) — matches reference unless two true distances
// differ by <2^-14 relative (rare for random points).
#define MSTEP(K) { unsigned int t = min(key, K); key = max(key, K); K = t; }
__global__ __launch_bounds__(256) __attribute__((amdgpu_waves_per_eu(1, 4)))
void knn_partial_kernel(const float* __restrict__ xyz, float4* __restrict__ Pp) {
  __shared__ float4 sp[512];    // (x, y, z, |p|^2)
  int s  = blockIdx.x;          // candidate slice 0..7
  int qg = blockIdx.y;          // query group 0..63
  int b  = blockIdx.z;
  const float* base = xyz + (size_t)b * 3 * NPT;
  int c0 = s * 512;
  for (int i = threadIdx.x; i < 512; i += 256) {
    float mx = base[c0 + i], my = base[NPT + c0 + i], mz = base[2*NPT + c0 + i];
    sp[i] = make_float4(mx, my, mz, mx*mx + my*my + mz*mz);
  }
  int lane = threadIdx.x & 63;
  int wv   = threadIdx.x >> 6;
  int qn   = qg * 64 + lane;
  float qx = base[qn], qy = base[NPT + qn], qz = base[2*NPT + qn];
  float qsq = qx*qx + qy*qy + qz*qz;
  float qx2 = -2.f*qx, qy2 = -2.f*qy, qz2 = -2.f*qz;
  __syncthreads();

  unsigned int k0=0xFFFFFFFFu,k1=0xFFFFFFFFu,k2=0xFFFFFFFFu,k3=0xFFFFFFFFu,
               k4=0xFFFFFFFFu,k5=0xFFFFFFFFu,k6=0xFFFFFFFFu,k7=0xFFFFFFFFu,
               k8=0xFFFFFFFFu,k9=0xFFFFFFFFu,k10=0xFFFFFFFFu,k11=0xFFFFFFFFu,
               k12=0xFFFFFFFFu,k13=0xFFFFFFFFu,k14=0xFFFFFFFFu,k15=0xFFFFFFFFu;

  int mbase = wv * 128;
#pragma unroll 2
  for (int mm = 0; mm < 128; mm++) {
    int m = mbase + mm;
    float4 m4 = sp[m];                       // wave-uniform broadcast read
    float nd = fmaf(qx2, m4.x, fmaf(qy2, m4.y, fmaf(qz2, m4.z, m4.w + qsq)));
    nd = fmaxf(nd, 0.f);
    unsigned int key = (__float_as_uint(nd) & 0xFFFFFE00u) | (unsigned int)m;
    MSTEP(k0)  MSTEP(k1)  MSTEP(k2)  MSTEP(k3)
    MSTEP(k4)  MSTEP(k5)  MSTEP(k6)  MSTEP(k7)
    MSTEP(k8)  MSTEP(k9)  MSTEP(k10) MSTEP(k11)
    MSTEP(k12) MSTEP(k13) MSTEP(k14) MSTEP(k15)
  }

  int gq = b * NPT + qn;
  float4* out = Pp + (size_t)gq * 256 + (s*4 + wv)*8;   // 128B contiguous per thread
#define UNP(K) __uint_as_float(K & 0xFFFFFE00u), __int_as_float(c0 + (int)(K & 0x1FFu))
  out[0] = make_float4(UNP(k0),  UNP(k1));
  out[1] = make_float4(UNP(k2),  UNP(k3));
  out[2] = make_float4(UNP(k4),  UNP(k5));
  out[3] = make_float4(UNP(k6),  UNP(k7));
  out[4] = make_float4(UNP(k8),  UNP(k9));
  out[5] = make_float4(UNP(k10), UNP(k11));
  out[6] = make_float4(UNP(k12), UNP(k13));
  out[7] = make_float4(UNP(k14), UNP(k15));
#undef UNP
}

// ---------------- KNN stage 2: one WAVE per query, 8 entries/lane, 16 select-min rounds ----
__global__ __launch_bounds__(256)
void knn_merge_kernel(const float4* __restrict__ Pp, int* __restrict__ idx_out) {
  int wv   = threadIdx.x >> 6;
  int lane = threadIdx.x & 63;
  int gq   = blockIdx.x * 4 + wv;
  float d[8]; int ii[8];
  const float4* base = Pp + (size_t)gq * 256;
#pragma unroll
  for (int j = 0; j < 4; j++) {
    float4 v = base[j*64 + lane];
    d[2*j+0] = v.x; ii[2*j+0] = __float_as_int(v.y);
    d[2*j+1] = v.z; ii[2*j+1] = __float_as_int(v.w);
  }
  for (int sel = 0; sel < 16; sel++) {
    float bd = 3.5e38f; int bi = 0x7fffffff;
#pragma unroll
    for (int t = 0; t < 8; t++) {
      bool better = (d[t] < bd) || (d[t] == bd && ii[t] < bi);
      if (better) { bd = d[t]; bi = ii[t]; }
    }
#pragma unroll
    for (int off = 1; off < 64; off <<= 1) {
      float od = __shfl_xor(bd, off, 64);
      int   oi = __shfl_xor(bi, off, 64);
      if (od < bd || (od == bd && oi < bi)) { bd = od; bi = oi; }
    }
#pragma unroll
    for (int t = 0; t < 8; t++)
      if (ii[t] == bi) d[t] = 3.5e38f;
    if (lane == 0) idx_out[gq*16 + sel] = bi;
  }
}

// ---------------- fused rel-pos bias: 2 (n,k) pairs per thread, shared weight reads --
__global__ __launch_bounds__(256)
void bias_kernel(const float* __restrict__ xyz, const int* __restrict__ idx,
                 const float4* __restrict__ w1f, const float4* __restrict__ W2t,
                 float4* __restrict__ biasB) {
  __shared__ float4 sw1[256];
  __shared__ float4 sw2[256];
  int tid = threadIdx.x;
  sw1[tid] = w1f[tid];
  sw2[tid] = W2t[tid];
  __syncthreads();
  int gid0 = blockIdx.x * 512 + tid;     // (b*N + n)*K + k
  int gid1 = gid0 + 256;
  float rx0, ry0, rz0, rx1, ry1, rz1;
  {
    int b = gid0 >> 16, n = (gid0 >> 4) & 4095, j = idx[gid0];
    const float* base = xyz + (size_t)b * 3 * NPT;
    rx0 = base[j] - base[n];
    ry0 = base[NPT + j] - base[NPT + n];
    rz0 = base[2*NPT + j] - base[2*NPT + n];
  }
  {
    int b = gid1 >> 16, n = (gid1 >> 4) & 4095, j = idx[gid1];
    const float* base = xyz + (size_t)b * 3 * NPT;
    rx1 = base[j] - base[n];
    ry1 = base[NPT + j] - base[NPT + n];
    rz1 = base[2*NPT + j] - base[2*NPT + n];
  }
  float a00=0.f,a01=0.f,a02=0.f,a03=0.f;
  float a10=0.f,a11=0.f,a12=0.f,a13=0.f;
#pragma unroll 4
  for (int c = 0; c < 256; c++) {
    float4 w  = sw1[c];
    float4 w2 = sw2[c];
    float t0 = fmaxf(fmaf(rx0, w.x, fmaf(ry0, w.y, fmaf(rz0, w.z, w.w))), 0.f);
    float t1 = fmaxf(fmaf(rx1, w.x, fmaf(ry1, w.y, fmaf(rz1, w.z, w.w))), 0.f);
    a00 = fmaf(t0, w2.x, a00); a01 = fmaf(t0, w2.y, a01);
    a02 = fmaf(t0, w2.z, a02); a03 = fmaf(t0, w2.w, a03);
    a10 = fmaf(t1, w2.x, a10); a11 = fmaf(t1, w2.y, a11);
    a12 = fmaf(t1, w2.z, a12); a13 = fmaf(t1, w2.w, a13);
  }
  biasB[gid0] = make_float4(a00, a01, a02, a03);
  biasB[gid1] = make_float4(a10, a11, a12, a13);
}

// ---------------- fused attention v2: lane = (neighbor k, 16-ch chunk) -------------
__global__ __launch_bounds__(256, 4)
void attn_kernel(const unsigned short* __restrict__ qkv, const float* __restrict__ biasB,
                 const int* __restrict__ idx, unsigned short* __restrict__ attn_b) {
  __shared__ int sidx[16];
  __shared__ float red[4][16*68];   // per-wave [k][68] rows, 17408 B total
  int bn = blockIdx.x;
  int b  = bn >> 12;
  if (threadIdx.x < 16) sidx[threadIdx.x] = idx[bn*16 + threadIdx.x];
  __syncthreads();
  int wv   = threadIdx.x >> 6;      // head
  int lane = threadIdx.x & 63;
  int k    = lane >> 2;             // neighbor
  int c4   = lane & 3;              // channel chunk
  int ch0  = wv*64 + c4*16;
  size_t rowq = (size_t)bn * 768;
  size_t base = (size_t)(b*NPT) * 768;

  float qf[16];
  {
    uint4 q0 = *(const uint4*)(qkv + rowq + ch0);
    uint4 q1 = *(const uint4*)(qkv + rowq + ch0 + 8);
    up16(q0, q1, qf);
  }
  int j = sidx[k];
  float dot = 0.f;
  {
    const unsigned short* krow = qkv + base + (size_t)j*768 + 256 + ch0;
    uint4 k0 = *(const uint4*)(krow);
    uint4 k1 = *(const uint4*)(krow + 8);
    float kf[16];
    up16(k0, k1, kf);
#pragma unroll
    for (int i = 0; i < 16; i++) dot = fmaf(qf[i], kf[i], dot);
  }
  dot += __shfl_xor(dot, 1, 64);
  dot += __shfl_xor(dot, 2, 64);
  float logit = dot * 0.125f + biasB[(size_t)(bn*16 + k)*4 + wv];
  float mx = logit;
#pragma unroll
  for (int off = 4; off < 64; off <<= 1) mx = fmaxf(mx, __shfl_xor(mx, off, 64));
  float e = __expf(logit - mx);
  float ssum = e;
#pragma unroll
  for (int off = 4; off < 64; off <<= 1) ssum += __shfl_xor(ssum, off, 64);
  float w = e / ssum;

  {
    const unsigned short* vrow = qkv + base + (size_t)j*768 + 512 + ch0;
    uint4 v0 = *(const uint4*)(vrow);
    uint4 v1 = *(const uint4*)(vrow + 8);
    float vf[16];
    up16(v0, v1, vf);
    float* dst = &red[wv][k*68 + c4*16];
#pragma unroll
    for (int g = 0; g < 4; g++)
      ((float4*)dst)[g] = make_float4(w*vf[g*4], w*vf[g*4+1], w*vf[g*4+2], w*vf[g*4+3]);
  }
  __syncthreads();
  float o = 0.f;
#pragma unroll
  for (int kk = 0; kk < 16; kk++) o += red[wv][kk*68 + lane];   // 2-way = free
  attn_b[(size_t)bn*256 + wv*64 + lane] = f2b(o);
}

// ---------------- MFMA bf16 GEMM: D[n][m] = A[n][k] * W[m][k] ----------------
struct MG {
  const unsigned short* A; const unsigned short* Wt; int K; int M;
  unsigned short* OutB; float* OutF;
  const float* bias; const float* resid;
  const float* bng; const float* bnb; const float* bnm; const float* bnv;
};

template<int EPI>
__global__ __launch_bounds__(256)
void mgemm_kernel(MG p) {
  __shared__ unsigned short As[128][40];
  __shared__ unsigned short Bs[64][40];
  const int tid  = threadIdx.x;
  const int bb   = blockIdx.z;
  const int n0   = blockIdx.x * 128;
  const int m0   = blockIdx.y * 64;
  const int lane = tid & 63;
  const int wv   = tid >> 6;
  const int l15  = lane & 15;
  const int quad = lane >> 4;
  const int K    = p.K;

  f32x4 acc[2][4];
#pragma unroll
  for (int i = 0; i < 2; i++)
#pragma unroll
    for (int j = 0; j < 4; j++) acc[i][j] = (f32x4){0.f, 0.f, 0.f, 0.f};

  const int arow = tid >> 1, ahalf = tid & 1;
  const int wrow = tid >> 2, wseg = tid & 3;
  const unsigned short* Ap = p.A  + (size_t)(bb*NPT + n0 + arow)*K + ahalf*16;
  const unsigned short* Wp = p.Wt + (size_t)(m0 + wrow)*K + wseg*8;

  for (int c0 = 0; c0 < K; c0 += 32) {
    uint4 va0 = *(const uint4*)(Ap + c0);
    uint4 va1 = *(const uint4*)(Ap + c0 + 8);
    uint4 vw  = *(const uint4*)(Wp + c0);
    *(uint4*)&As[arow][ahalf*16]     = va0;
    *(uint4*)&As[arow][ahalf*16 + 8] = va1;
    *(uint4*)&Bs[wrow][wseg*8]       = vw;
    __syncthreads();
    short8 bf[4];
#pragma unroll
    for (int mt = 0; mt < 4; mt++)
      bf[mt] = *(const short8*)&Bs[mt*16 + l15][quad*8];
#pragma unroll
    for (int nt = 0; nt < 2; nt++) {
      short8 af = *(const short8*)&As[wv*32 + nt*16 + l15][quad*8];
#pragma unroll
      for (int mt = 0; mt < 4; mt++)
        acc[nt][mt] = __builtin_amdgcn_mfma_f32_16x16x32_bf16(af, bf[mt], acc[nt][mt], 0, 0, 0);
    }
    __syncthreads();
  }

  if (EPI == 0 || EPI == 1) {
    float bs[4];
#pragma unroll
    for (int mt = 0; mt < 4; mt++)
      bs[mt] = (EPI == 1) ? p.bias[m0 + mt*16 + l15] : 0.f;
#pragma unroll
    for (int nt = 0; nt < 2; nt++)
#pragma unroll
      for (int reg = 0; reg < 4; reg++) {
        size_t row = ((size_t)(bb*NPT + n0 + wv*32 + nt*16 + quad*4 + reg))*p.M + m0;
#pragma unroll
        for (int mt = 0; mt < 4; mt++) {
          float v = acc[nt][mt][reg] + bs[mt];
          if (EPI == 1) v = fmaxf(v, 0.f);
          p.OutB[row + mt*16 + l15] = f2b(v);
        }
      }
  } else if (EPI == 2) {
    float sc[4], sh[4];
#pragma unroll
    for (int mt = 0; mt < 4; mt++) {
      int m = m0 + mt*16 + l15;
      float s = p.bng[m] / sqrtf(p.bnv[m] + EPSBN);
      sc[mt] = s; sh[mt] = p.bnb[m] - p.bnm[m]*s;
    }
#pragma unroll
    for (int nt = 0; nt < 2; nt++)
#pragma unroll
      for (int reg = 0; reg < 4; reg++) {
        size_t row = ((size_t)(bb*NPT + n0 + wv*32 + nt*16 + quad*4 + reg))*p.M + m0;
#pragma unroll
        for (int mt = 0; mt < 4; mt++) {
          float r = p.resid[row + mt*16 + l15];
          float v = (acc[nt][mt][reg] + r)*sc[mt] + sh[mt];
          p.OutF[row + mt*16 + l15] = v;
          p.OutB[row + mt*16 + l15] = f2b(v);
        }
      }
  } else {  // EPI == 3
    __shared__ float Tb[4][4][16*17];
    float sc[4], sh[4], bs[4];
#pragma unroll
    for (int mt = 0; mt < 4; mt++) {
      int m = m0 + mt*16 + l15;
      float s = p.bng[m] / sqrtf(p.bnv[m] + EPSBN);
      sc[mt] = s; sh[mt] = p.bnb[m] - p.bnm[m]*s;
      bs[mt] = p.bias[m];
    }
#pragma unroll
    for (int nt = 0; nt < 2; nt++) {
#pragma unroll
      for (int reg = 0; reg < 4; reg++) {
        size_t row = ((size_t)(bb*NPT + n0 + wv*32 + nt*16 + quad*4 + reg))*p.M + m0;
#pragma unroll
        for (int mt = 0; mt < 4; mt++) {
          float r = p.resid[row + mt*16 + l15];
          float v = (acc[nt][mt][reg] + bs[mt] + r)*sc[mt] + sh[mt];
          Tb[wv][mt][(quad*4 + reg)*17 + l15] = v;
        }
      }
      __syncthreads();
#pragma unroll
      for (int mt = 0; mt < 4; mt++)
#pragma unroll
        for (int reg = 0; reg < 4; reg++) {
          float v = Tb[wv][mt][l15*17 + quad*4 + reg];
          p.OutF[((size_t)(bb*p.M + m0 + mt*16 + quad*4 + reg))*NPT
                 + n0 + wv*32 + nt*16 + l15] = v;
        }
      __syncthreads();
    }
  }
}

extern "C" void kernel_launch(void* const* d_in, const int* in_sizes, int n_in,
                              void* d_out, int out_size, void* d_ws, size_t ws_size,
                              hipStream_t stream) {
  const float* x     = (const float*)d_in[0];
  const float* xyz   = (const float*)d_in[1];
  const float* Wq    = (const float*)d_in[2];
  const float* Wkv   = (const float*)d_in[3];
  const float* Wproj = (const float*)d_in[4];
  const float* rp_w1 = (const float*)d_in[5];
  const float* rp_g  = (const float*)d_in[6];
  const float* rp_b  = (const float*)d_in[7];
  const float* rp_m  = (const float*)d_in[8];
  const float* rp_v  = (const float*)d_in[9];
  const float* rp_w2 = (const float*)d_in[10];
  const float* bn1_g = (const float*)d_in[11];
  const float* bn1_b = (const float*)d_in[12];
  const float* bn1_m = (const float*)d_in[13];
  const float* bn1_v = (const float*)d_in[14];
  const float* bn2_g = (const float*)d_in[15];
  const float* bn2_b = (const float*)d_in[16];
  const float* bn2_m = (const float*)d_in[17];
  const float* bn2_v = (const float*)d_in[18];
  const float* ffn_w1 = (const float*)d_in[19];
  const float* ffn_b1 = (const float*)d_in[20];
  const float* ffn_w2 = (const float*)d_in[21];
  const float* ffn_b2 = (const float*)d_in[22];

  char* ws = (char*)d_ws;
  // static region
  float4* w1f = (float4*)(ws + 0);                         //   4 KB
  float4* W2t = (float4*)(ws + 4096);                      //   4 KB
  int*    idx = (int*)  (ws + 8192);                       // 512 KB
  // reuse region A (32 MB): KNN scratch first, then post-attn tensors
  const size_t oA = 532480;
  float4*         Pp     = (float4*)(ws + oA);             // 32 MB [B*N][512] (d,idx)
  unsigned short* attn_b = (unsigned short*)(ws + oA);                 //  4 MB bf16 [B][N][256]
  float*          x1f    = (float*)(ws + oA + (4u<<20));               //  8 MB fp32 [B][N][256]
  unsigned short* x1b    = (unsigned short*)(ws + oA + (12u<<20));     //  4 MB bf16 [B][N][256]
  unsigned short* h_b    = (unsigned short*)(ws + oA + (16u<<20));     // 16 MB bf16 [B][N][1024]
  // region B: weights + casted x + qkv + bias
  const size_t oB = oA + (32u<<20);
  unsigned short* Wqkv_b  = (unsigned short*)(ws + oB);                // 384 KB [768][256]
  unsigned short* Wproj_b = (unsigned short*)(ws + oB + 393216);       // 128 KB
  unsigned short* W1_b    = (unsigned short*)(ws + oB + 524288);       // 512 KB
  unsigned short* W2_b    = (unsigned short*)(ws + oB + 1048576);      // 512 KB
  unsigned short* xb      = (unsigned short*)(ws + oB + 1572864);      //   4 MB bf16 [B][N][256]
  float*          xf      = (float*)(ws + oB + 1572864 + (4u<<20));    //   8 MB fp32 [B][N][256]
  unsigned short* qkv     = (unsigned short*)(ws + oB + 1572864 + (12u<<20)); // 12 MB bf16 [B][N][768]
  float*          biasB   = (float*)(ws + oB + 1572864 + (24u<<20));   //   2 MB [B][N][16][4]

  prep_kernel<<<1, 256, 0, stream>>>(rp_w1, rp_g, rp_b, rp_m, rp_v, rp_w2, w1f, W2t);
  wcast_kernel<<<3072, 256, 0, stream>>>(Wq, Wkv, Wproj, ffn_w1, ffn_w2,
                                         Wqkv_b, Wproj_b, W1_b, W2_b);
  xcast_kernel<<<dim3(64, 4, BB), 256, 0, stream>>>(x, xb, xf);

  knn_partial_kernel<<<dim3(8, 64, BB), 256, 0, stream>>>(xyz, Pp);
  knn_merge_kernel<<<(BB*NPT)/4, 256, 0, stream>>>(Pp, idx);

  MG pqkv = {xb, Wqkv_b, 256, 768, qkv, nullptr,
             nullptr, nullptr, nullptr, nullptr, nullptr, nullptr};
  mgemm_kernel<0><<<dim3(32, 12, BB), 256, 0, stream>>>(pqkv);

  bias_kernel<<<(BB*NPT*KNN)/512, 256, 0, stream>>>(xyz, idx, w1f, W2t, (float4*)biasB);
  attn_kernel<<<BB*NPT, 256, 0, stream>>>(qkv, biasB, idx, attn_b);

  MG pproj = {attn_b, Wproj_b, 256, 256, x1b, x1f,
              nullptr, xf, bn1_g, bn1_b, bn1_m, bn1_v};
  mgemm_kernel<2><<<dim3(32, 4, BB), 256, 0, stream>>>(pproj);

  MG pf1 = {x1b, W1_b, 256, 1024, h_b, nullptr,
            ffn_b1, nullptr, nullptr, nullptr, nullptr, nullptr};
  mgemm_kernel<1><<<dim3(32, 16, BB), 256, 0, stream>>>(pf1);

  MG pf2 = {h_b, W2_b, 1024, 256, nullptr, (float*)d_out,
            ffn_b2, x1f, bn2_g, bn2_b, bn2_m, bn2_v};
  mgemm_kernel<3><<<dim3(32, 4, BB), 256, 0, stream>>>(pf2);
}